// Round 21
// baseline (921.096 us; speedup 1.0000x reference)
//
#include <hip/hip_runtime.h>
#include <hip/hip_bf16.h>
#include <cstdint>

constexpr int B_ = 4;
constexpr int S_ = 2048;
constexpr int D_ = 512;
constexpr int H_ = 8;
constexpr int DK_ = 64;
constexpr int M_ = B_ * S_;

typedef __attribute__((ext_vector_type(8))) short bf16x8;
typedef __attribute__((ext_vector_type(4))) short bf16x4;
typedef __attribute__((ext_vector_type(4))) float f32x4;

__device__ __forceinline__ unsigned short f2bf(float x) {
    unsigned u = __float_as_uint(x);
    return (unsigned short)((u + 0x7fffu + ((u >> 16) & 1u)) >> 16);
}
__device__ __forceinline__ float bf2f(unsigned short h) {
    return __uint_as_float(((unsigned)h) << 16);
}

#define MFMA32(a, b, c) __builtin_amdgcn_mfma_f32_16x16x32_bf16(a, b, c, 0, 0, 0)

// ---------------------------------------------------------------------------
// cvt body (verified): fp32 -> hi/lo bf16 at linear idx
// ---------------------------------------------------------------------------
__device__ __forceinline__ void cvt_body(const float* __restrict__ X,
                                         short* __restrict__ Xh,
                                         short* __restrict__ Xl, size_t idx) {
    float4 v0 = *reinterpret_cast<const float4*>(X + idx);
    float4 v1 = *reinterpret_cast<const float4*>(X + idx + 4);
    float f[8] = {v0.x, v0.y, v0.z, v0.w, v1.x, v1.y, v1.z, v1.w};
    short hh[8], ll[8];
#pragma unroll
    for (int e = 0; e < 8; ++e) {
        unsigned short hb = f2bf(f[e]);
        hh[e] = (short)hb;
        ll[e] = (short)f2bf(f[e] - bf2f(hb));
    }
    *(bf16x4*)(Xh + idx)     = (bf16x4){hh[0], hh[1], hh[2], hh[3]};
    *(bf16x4*)(Xh + idx + 4) = (bf16x4){hh[4], hh[5], hh[6], hh[7]};
    *(bf16x4*)(Xl + idx)     = (bf16x4){ll[0], ll[1], ll[2], ll[3]};
    *(bf16x4*)(Xl + idx + 4) = (bf16x4){ll[4], ll[5], ll[6], ll[7]};
}

// cvt_qkv: grid (2048, 3) -> q,k,v
__global__ __launch_bounds__(256) void cvt_qkv(
    const float* __restrict__ q, const float* __restrict__ k,
    const float* __restrict__ v,
    short* __restrict__ qh, short* __restrict__ ql,
    short* __restrict__ kh, short* __restrict__ kl,
    short* __restrict__ vh, short* __restrict__ vl) {
    const float* X; short *Xh, *Xl;
    if (blockIdx.y == 0)      { X = q; Xh = qh; Xl = ql; }
    else if (blockIdx.y == 1) { X = k; Xh = kh; Xl = kl; }
    else                      { X = v; Xh = vh; Xl = vl; }
    cvt_body(X, Xh, Xl, ((size_t)blockIdx.x * 256 + threadIdx.x) * 8);
}

// cvt_w: grid (128, 4) -> w_q, w_k, w_v, w_o
__global__ __launch_bounds__(256) void cvt_w(
    const float* __restrict__ wq, const float* __restrict__ wk,
    const float* __restrict__ wv, const float* __restrict__ wo,
    short* __restrict__ qh, short* __restrict__ ql,
    short* __restrict__ kh, short* __restrict__ kl,
    short* __restrict__ vh, short* __restrict__ vl,
    short* __restrict__ oh, short* __restrict__ ol) {
    const float* X; short *Xh, *Xl;
    if (blockIdx.y == 0)      { X = wq; Xh = qh; Xl = ql; }
    else if (blockIdx.y == 1) { X = wk; Xh = kh; Xl = kl; }
    else if (blockIdx.y == 2) { X = wv; Xh = vh; Xl = vl; }
    else                      { X = wo; Xh = oh; Xl = ol; }
    cvt_body(X, Xh, Xl, ((size_t)blockIdx.x * 256 + threadIdx.x) * 8);
}

// ---------------------------------------------------------------------------
// stage_bf (verified)
// ---------------------------------------------------------------------------
__device__ __forceinline__ void stage_bf(const short* __restrict__ srcH,
                                         const short* __restrict__ srcL,
                                         short* Hh, short* Hl, int tid, int rows) {
#pragma unroll
    for (int p = 0; p < rows / 32; ++p) {
        int idx = tid + p * 256;
        int r = idx >> 3;
        int cc = idx & 7;
        int off = r * 64 + ((cc ^ (r & 7)) << 3);
        *(bf16x8*)(Hh + off) = *(const bf16x8*)(srcH + (size_t)r * 512 + cc * 8);
        *(bf16x8*)(Hl + off) = *(const bf16x8*)(srcL + (size_t)r * 512 + cc * 8);
    }
}

// ---------------------------------------------------------------------------
// gemm_bf: C[m][n] = sum_k A[m][k]*W[n][k], pre-converted hi/lo bf16 inputs.
// EPI 0: fp32 C.  EPI 1: head-major hi/lo (Q/K).  EPI 2: head-major V^T bf16.
// ---------------------------------------------------------------------------
template <int EPI>
__global__ __launch_bounds__(256) void gemm_bf(const short* __restrict__ Ah_g,
                                               const short* __restrict__ Al_g,
                                               const short* __restrict__ Wh_g,
                                               const short* __restrict__ Wl_g,
                                               float* __restrict__ C,
                                               short* __restrict__ Ch,
                                               short* __restrict__ Cl) {
    __shared__ __align__(16) short Ah[8192];
    __shared__ __align__(16) short Al[8192];
    __shared__ __align__(16) short Wh[4096];
    __shared__ __align__(16) short Wl[4096];

    const int tid = threadIdx.x;
    const int wave = tid >> 6;
    const int lane = tid & 63;
    const int lg = lane >> 4;
    const int lr = lane & 15;
    const int bm = blockIdx.x * 128;
    const int bn = blockIdx.y * 64;

    f32x4 acc[2][4];
#pragma unroll
    for (int s = 0; s < 2; ++s)
#pragma unroll
        for (int n = 0; n < 4; ++n) acc[s][n] = (f32x4){0.f, 0.f, 0.f, 0.f};

    for (int k0 = 0; k0 < 512; k0 += 64) {
        stage_bf(Ah_g + (size_t)bm * 512 + k0, Al_g + (size_t)bm * 512 + k0, Ah, Al, tid, 128);
        stage_bf(Wh_g + (size_t)bn * 512 + k0, Wl_g + (size_t)bn * 512 + k0, Wh, Wl, tid, 64);
        __syncthreads();

#pragma unroll
        for (int ks = 0; ks < 2; ++ks) {
            bf16x8 ah[2], al[2];
#pragma unroll
            for (int sub = 0; sub < 2; ++sub) {
                int r = wave * 32 + sub * 16 + lr;
                int off = r * 64 + (((ks * 4 + lg) ^ (r & 7)) << 3);
                ah[sub] = *(const bf16x8*)(Ah + off);
                al[sub] = *(const bf16x8*)(Al + off);
            }
#pragma unroll
            for (int nsub = 0; nsub < 4; ++nsub) {
                int r = nsub * 16 + lr;
                int off = r * 64 + (((ks * 4 + lg) ^ (r & 7)) << 3);
                bf16x8 wh = *(const bf16x8*)(Wh + off);
                bf16x8 wl = *(const bf16x8*)(Wl + off);
#pragma unroll
                for (int sub = 0; sub < 2; ++sub) {
                    acc[sub][nsub] = MFMA32(ah[sub], wh, acc[sub][nsub]);
                    acc[sub][nsub] = MFMA32(ah[sub], wl, acc[sub][nsub]);
                    acc[sub][nsub] = MFMA32(al[sub], wh, acc[sub][nsub]);
                }
            }
        }
        __syncthreads();
    }

    if (EPI == 2) {
#pragma unroll
        for (int sub = 0; sub < 2; ++sub)
#pragma unroll
            for (int nsub = 0; nsub < 4; ++nsub)
#pragma unroll
                for (int rr = 0; rr < 4; ++rr) {
                    int rloc = wave * 32 + sub * 16 + lg * 4 + rr;
                    int cloc = nsub * 16 + lr;
                    short bv = (short)f2bf(acc[sub][nsub][rr]);
                    if (rloc < 64) Ah[rloc * 66 + cloc] = bv;
                    else           Al[(rloc - 64) * 66 + cloc] = bv;
                }
        __syncthreads();
        const int dk = tid >> 2;
        const int j0l = (tid & 3) * 32;
        const short* src = (j0l < 64) ? Ah : Al;
        const int jb = j0l & 63;
        const int h = bn >> 6;
        const int bq = bm >> 11;
        short* dst = Ch + ((size_t)((bq * 8 + h) * 64 + dk)) * 2048 + (bm & 2047) + j0l;
#pragma unroll
        for (int qq = 0; qq < 4; ++qq) {
            bf16x8 o;
#pragma unroll
            for (int e = 0; e < 8; ++e)
                o[e] = src[(jb + qq * 8 + e) * 66 + dk];
            *(bf16x8*)(dst + qq * 8) = o;
        }
        return;
    }

#pragma unroll
    for (int sub = 0; sub < 2; ++sub)
#pragma unroll
        for (int nsub = 0; nsub < 4; ++nsub)
#pragma unroll
            for (int rr = 0; rr < 4; ++rr) {
                int row = bm + wave * 32 + sub * 16 + lg * 4 + rr;
                int col = bn + nsub * 16 + lr;
                float a = acc[sub][nsub][rr];
                if (EPI == 0) {
                    C[(size_t)row * 512 + col] = a;
                } else {
                    unsigned short hb = f2bf(a);
                    size_t off = (((size_t)(row >> 11) * 8 + (col >> 6)) * 2048 +
                                  (row & 2047)) * 64 + (col & 63);
                    Ch[off] = (short)hb;
                    Cl[off] = (short)f2bf(a - bf2f(hb));
                }
            }
}

// ---------------------------------------------------------------------------
// mask_pack (unchanged)
// ---------------------------------------------------------------------------
__global__ __launch_bounds__(256) void mask_pack(const int* __restrict__ mask,
                                                 unsigned long long* __restrict__ pk) {
    const int row = blockIdx.x;
    const int tid = threadIdx.x;
    const int* mrow = mask + (size_t)row * 2048;
#pragma unroll
    for (int p = 0; p < 8; ++p) {
        int j = p * 256 + tid;
        unsigned long long bal = __ballot(mrow[j] != 0);
        if ((tid & 63) == 0) pk[(size_t)row * 32 + p * 4 + (tid >> 6)] = bal;
    }
}

// ---------------------------------------------------------------------------
// Fused attention: round-17/20 verified kernel; ONE change: P stores are
// nontemporal (bypass L2 allocation; P is write-once, never re-read).
// ---------------------------------------------------------------------------
__global__ __launch_bounds__(256, 3) void fused_attn(
    const short* __restrict__ Qh_g, const short* __restrict__ Ql_g,
    const short* __restrict__ Kh_g, const short* __restrict__ Kl_g,
    const short* __restrict__ Vt_g, const unsigned long long* __restrict__ pk,
    float* __restrict__ P, short* __restrict__ Aho, short* __restrict__ Alo) {
    __shared__ __align__(16) short Kbuf[2][2][4096];
    __shared__ __align__(16) short Wt[4096];

    const int tid = threadIdx.x;
    const int wave = tid >> 6;
    const int lane = tid & 63;
    const int lg = lane >> 4;
    const int lr = lane & 15;

    const int wgid = blockIdx.y * 32 + blockIdx.x;
    const int xcd = wgid & 7;
    const int slot = wgid >> 3;
    const int bh = xcd * 4 + (slot & 3);
    const int i0 = (slot >> 2) * 64;
    const int b = bh >> 3;

    bf16x8 qh[2], ql[2];
    {
        const size_t qbase = ((size_t)bh * 2048 + i0 + wave * 16 + lr) * 64;
#pragma unroll
        for (int ks = 0; ks < 2; ++ks) {
            qh[ks] = *(const bf16x8*)(Qh_g + qbase + (ks * 4 + lg) * 8);
            ql[ks] = *(const bf16x8*)(Ql_g + qbase + (ks * 4 + lg) * 8);
        }
    }

    const int o0 = tid * 16;
    const int o1 = 4096 + tid * 16;
    const int s0 = o0 ^ (((o0 >> 7) & 7) << 4);
    const int s1 = o1 ^ (((o1 >> 7) & 7) << 4);

    bf16x8 Rh0, Rh1, Rl0, Rl1;
#define LOADKH(t)                                                           \
    {                                                                       \
        const short* bKh = Kh_g + ((size_t)bh * 2048 + (t) * 64) * 64;      \
        Rh0 = *(const bf16x8*)(bKh + (o0 >> 1));                            \
        Rh1 = *(const bf16x8*)(bKh + (o1 >> 1));                            \
    }
#define WRITEKH(cur)                                                        \
    {                                                                       \
        *(bf16x8*)(&Kbuf[cur][0][0] + (s0 >> 1)) = Rh0;                     \
        *(bf16x8*)(&Kbuf[cur][0][0] + (s1 >> 1)) = Rh1;                     \
    }
#define LOADK(t)                                                            \
    {                                                                       \
        const short* bKh = Kh_g + ((size_t)bh * 2048 + (t) * 64) * 64;      \
        const short* bKl = Kl_g + ((size_t)bh * 2048 + (t) * 64) * 64;      \
        Rh0 = *(const bf16x8*)(bKh + (o0 >> 1));                            \
        Rh1 = *(const bf16x8*)(bKh + (o1 >> 1));                            \
        Rl0 = *(const bf16x8*)(bKl + (o0 >> 1));                            \
        Rl1 = *(const bf16x8*)(bKl + (o1 >> 1));                            \
    }
#define WRITEK(cur)                                                         \
    {                                                                       \
        *(bf16x8*)(&Kbuf[cur][0][0] + (s0 >> 1)) = Rh0;                     \
        *(bf16x8*)(&Kbuf[cur][0][0] + (s1 >> 1)) = Rh1;                     \
        *(bf16x8*)(&Kbuf[cur][1][0] + (s0 >> 1)) = Rl0;                     \
        *(bf16x8*)(&Kbuf[cur][1][0] + (s1 >> 1)) = Rl1;                     \
    }

    const size_t pkrow = (size_t)b * 2048 + i0 + wave * 16 + lg * 4;

    // ===== sweep 1 (lite): l = sum_j exp(s_hi) per row, no max shift =====
    float l_[4] = {0.f, 0.f, 0.f, 0.f};

    LOADKH(0);
    for (int t = 0; t < 32; ++t) {
        const int cur = t & 1;
        WRITEKH(cur);
        if (t < 31) LOADKH(t + 1);
        unsigned long long pkv[4];
#pragma unroll
        for (int rr = 0; rr < 4; ++rr) pkv[rr] = pk[(pkrow + rr) * 32 + t];
        __syncthreads();

        const short* KH = &Kbuf[cur][0][0];
#pragma unroll
        for (int jt = 0; jt < 4; ++jt) {
            f32x4 s = (f32x4){0.f, 0.f, 0.f, 0.f};
            int r = jt * 16 + lr;
#pragma unroll
            for (int ks = 0; ks < 2; ++ks) {
                int off = (r * 128 + (ks * 4 + lg) * 16) ^ ((r & 7) << 4);
                bf16x8 kh = *(const bf16x8*)(KH + (off >> 1));
                s = MFMA32(qh[ks], kh, s);
            }
#pragma unroll
            for (int rr = 0; rr < 4; ++rr) {
                bool mk = (pkv[rr] >> (jt * 16 + lr)) & 1ull;
                l_[rr] += mk ? 0.f : __expf(s[rr] * 0.125f);
            }
        }
    }

    // cross-lane sum of l over the 16 lr lanes
#pragma unroll
    for (int rr = 0; rr < 4; ++rr) {
        float l = l_[rr];
#pragma unroll
        for (int d = 1; d < 16; d <<= 1) l += __shfl_xor(l, d);
        l_[rr] = l;
    }

    float invl[4];
#pragma unroll
    for (int rr = 0; rr < 4; ++rr) invl[rr] = 1.0f / fmaxf(l_[rr], 1e-37f);

    // ====================== sweep 2: weights + P + PV ======================
    f32x4 Oa[4];
#pragma unroll
    for (int dt = 0; dt < 4; ++dt) Oa[dt] = (f32x4){0.f, 0.f, 0.f, 0.f};

    LOADK(0);
    for (int t = 0; t < 32; ++t) {
        const int cur = t & 1;
        WRITEK(cur);
        if (t < 31) LOADK(t + 1);
        unsigned long long pkv[4];
#pragma unroll
        for (int rr = 0; rr < 4; ++rr) pkv[rr] = pk[(pkrow + rr) * 32 + t];
        bf16x8 vf[4][2];
#pragma unroll
        for (int dt = 0; dt < 4; ++dt)
#pragma unroll
            for (int ks2 = 0; ks2 < 2; ++ks2)
                vf[dt][ks2] = *(const bf16x8*)(Vt_g +
                    ((size_t)(bh * 64 + dt * 16 + lr)) * 2048 + t * 64 + (ks2 * 4 + lg) * 8);
        __syncthreads();

        const short* KH = &Kbuf[cur][0][0];
        const short* KL = &Kbuf[cur][1][0];
#pragma unroll
        for (int jt = 0; jt < 4; ++jt) {
            f32x4 s = (f32x4){0.f, 0.f, 0.f, 0.f};
            int r = jt * 16 + lr;
#pragma unroll
            for (int ks = 0; ks < 2; ++ks) {
                int off = (r * 128 + (ks * 4 + lg) * 16) ^ ((r & 7) << 4);
                bf16x8 kh = *(const bf16x8*)(KH + (off >> 1));
                bf16x8 kl = *(const bf16x8*)(KL + (off >> 1));
                s = MFMA32(qh[ks], kh, s);
                s = MFMA32(qh[ks], kl, s);
                s = MFMA32(ql[ks], kh, s);
            }
#pragma unroll
            for (int rr = 0; rr < 4; ++rr) {
                bool mk = (pkv[rr] >> (jt * 16 + lr)) & 1ull;
                float w = mk ? 0.f : __expf(s[rr] * 0.125f) * invl[rr];
                int rw = wave * 16 + lg * 4 + rr;
                int wo = rw * 64 + (((jt * 2 + (lr >> 3)) ^ (rw & 7)) << 3) + (lr & 7);
                Wt[wo] = (short)f2bf(w);
            }
        }

        // P write: nontemporal (bypass L2 allocation; write-once stream)
        {
            int rp = wave * 16 + (lane >> 2);
            int c2 = (lane & 3) * 2;
            int po0 = rp * 64 + (((c2 + 0) ^ (rp & 7)) << 3);
            int po1 = rp * 64 + (((c2 + 1) ^ (rp & 7)) << 3);
            bf16x8 wa = *(const bf16x8*)(Wt + po0);
            bf16x8 wb = *(const bf16x8*)(Wt + po1);
            float* Prow = P + ((size_t)bh * 2048 + i0 + rp) * 2048 + t * 64 + (lane & 3) * 16;
#pragma unroll
            for (int q = 0; q < 2; ++q) {
                f32x4 oA = {bf2f((unsigned short)wa[q * 4 + 0]), bf2f((unsigned short)wa[q * 4 + 1]),
                            bf2f((unsigned short)wa[q * 4 + 2]), bf2f((unsigned short)wa[q * 4 + 3])};
                f32x4 oB = {bf2f((unsigned short)wb[q * 4 + 0]), bf2f((unsigned short)wb[q * 4 + 1]),
                            bf2f((unsigned short)wb[q * 4 + 2]), bf2f((unsigned short)wb[q * 4 + 3])};
                __builtin_nontemporal_store(oA, (f32x4*)(Prow + q * 4));
                __builtin_nontemporal_store(oB, (f32x4*)(Prow + 8 + q * 4));
            }
        }

        // PV: A-frag = wave's own Wt rows, B-frag = V^T registers
        bf16x8 aw[2];
#pragma unroll
        for (int ks2 = 0; ks2 < 2; ++ks2) {
            int ra = wave * 16 + lr;
            int ao = ra * 64 + (((ks2 * 4 + lg) ^ (ra & 7)) << 3);
            aw[ks2] = *(const bf16x8*)(Wt + ao);
        }
#pragma unroll
        for (int dt = 0; dt < 4; ++dt)
#pragma unroll
            for (int ks2 = 0; ks2 < 2; ++ks2)
                Oa[dt] = MFMA32(aw[ks2], vf[dt][ks2], Oa[dt]);
    }

    // context out as hi/lo bf16 rowmajor [8192][512]
    {
        const int h = bh & 7;
#pragma unroll
        for (int dt = 0; dt < 4; ++dt)
#pragma unroll
            for (int rr = 0; rr < 4; ++rr) {
                int gi = i0 + wave * 16 + lg * 4 + rr;
                size_t off = ((size_t)(b * 2048 + gi)) * 512 + h * 64 + dt * 16 + lr;
                float a = Oa[dt][rr];
                unsigned short hb = f2bf(a);
                Aho[off] = (short)hb;
                Alo[off] = (short)f2bf(a - bf2f(hb));
            }
    }
#undef LOADKH
#undef WRITEKH
#undef LOADK
#undef WRITEK
}

// ---------------------------------------------------------------------------
extern "C" void kernel_launch(void* const* d_in, const int* in_sizes, int n_in,
                              void* d_out, int out_size, void* d_ws, size_t ws_size,
                              hipStream_t stream) {
    const float* q   = (const float*)d_in[0];
    const float* k   = (const float*)d_in[1];
    const float* v   = (const float*)d_in[2];
    const int*   msk = (const int*)d_in[3];
    const float* w_q = (const float*)d_in[4];
    const float* w_k = (const float*)d_in[5];
    const float* w_v = (const float*)d_in[6];
    const float* w_o = (const float*)d_in[7];

    float* out = (float*)d_out;                 // [B,S,D]
    float* P   = out + (size_t)B_ * S_ * D_;    // [B,H,S,S]

    // ws layout (~96 MB)
    short* qh = (short*)d_ws;                   // [8192][512] bf16 hi (later context hi)
    short* ql = qh + (size_t)4194304;
    short* kh = ql + (size_t)4194304;
    short* kl = kh + (size_t)4194304;
    short* vh = kl + (size_t)4194304;
    short* vl = vh + (size_t)4194304;
    short* Qh = vl + (size_t)4194304;           // head-major
    short* Ql = Qh + (size_t)4194304;
    short* Kh = Ql + (size_t)4194304;
    short* Kl = Kh + (size_t)4194304;
    short* Vt = Kl + (size_t)4194304;           // [32][64][2048] bf16 (V^T)
    unsigned long long* pk = (unsigned long long*)(Vt + (size_t)4194304);
    short* wqh = (short*)(pk + (size_t)262144); // 512x512 each
    short* wql = wqh + (size_t)262144;
    short* wkh = wql + (size_t)262144;
    short* wkl = wkh + (size_t)262144;
    short* wvh = wkl + (size_t)262144;
    short* wvl = wvh + (size_t)262144;
    short* woh = wvl + (size_t)262144;
    short* wol = woh + (size_t)262144;

    dim3 blk(256);
    dim3 gproj(M_ / 128, D_ / 64);              // (64, 8)

    hipLaunchKernelGGL(cvt_qkv, dim3(2048, 3), blk, 0, stream,
                       q, k, v, qh, ql, kh, kl, vh, vl);
    hipLaunchKernelGGL(cvt_w, dim3(128, 4), blk, 0, stream,
                       w_q, w_k, w_v, w_o, wqh, wql, wkh, wkl, wvh, wvl, woh, wol);

    hipLaunchKernelGGL((gemm_bf<1>), gproj, blk, 0, stream, qh, ql, wqh, wql,
                       (float*)nullptr, Qh, Ql);
    hipLaunchKernelGGL((gemm_bf<1>), gproj, blk, 0, stream, kh, kl, wkh, wkl,
                       (float*)nullptr, Kh, Kl);
    hipLaunchKernelGGL((gemm_bf<2>), gproj, blk, 0, stream, vh, vl, wvh, wvl,
                       (float*)nullptr, Vt, (short*)nullptr);

    hipLaunchKernelGGL(mask_pack, dim3(M_), blk, 0, stream, msk, pk);

    // context written into qh/ql (dead after Q-gemm) as hi/lo bf16
    hipLaunchKernelGGL(fused_attn, dim3(32, 32), blk, 0, stream,
                       Qh, Ql, Kh, Kl, Vt, pk, P, qh, ql);

    hipLaunchKernelGGL((gemm_bf<0>), gproj, blk, 0, stream, qh, ql, woh, wol,
                       out, (short*)nullptr, (short*)nullptr);
}

// Round 22
// 450.118 us; speedup vs baseline: 2.0463x; 2.0463x over previous
//
#include <hip/hip_runtime.h>
#include <hip/hip_bf16.h>
#include <cstdint>

constexpr int B_ = 4;
constexpr int S_ = 2048;
constexpr int D_ = 512;
constexpr int H_ = 8;
constexpr int DK_ = 64;
constexpr int M_ = B_ * S_;

typedef __attribute__((ext_vector_type(8))) short bf16x8;
typedef __attribute__((ext_vector_type(4))) short bf16x4;
typedef __attribute__((ext_vector_type(4))) float f32x4;

__device__ __forceinline__ unsigned short f2bf(float x) {
    unsigned u = __float_as_uint(x);
    return (unsigned short)((u + 0x7fffu + ((u >> 16) & 1u)) >> 16);
}
__device__ __forceinline__ float bf2f(unsigned short h) {
    return __uint_as_float(((unsigned)h) << 16);
}

#define MFMA32(a, b, c) __builtin_amdgcn_mfma_f32_16x16x32_bf16(a, b, c, 0, 0, 0)

// ---------------------------------------------------------------------------
// cvt body (verified): fp32 -> hi/lo bf16 at linear idx
// ---------------------------------------------------------------------------
__device__ __forceinline__ void cvt_body(const float* __restrict__ X,
                                         short* __restrict__ Xh,
                                         short* __restrict__ Xl, size_t idx) {
    float4 v0 = *reinterpret_cast<const float4*>(X + idx);
    float4 v1 = *reinterpret_cast<const float4*>(X + idx + 4);
    float f[8] = {v0.x, v0.y, v0.z, v0.w, v1.x, v1.y, v1.z, v1.w};
    short hh[8], ll[8];
#pragma unroll
    for (int e = 0; e < 8; ++e) {
        unsigned short hb = f2bf(f[e]);
        hh[e] = (short)hb;
        ll[e] = (short)f2bf(f[e] - bf2f(hb));
    }
    *(bf16x4*)(Xh + idx)     = (bf16x4){hh[0], hh[1], hh[2], hh[3]};
    *(bf16x4*)(Xh + idx + 4) = (bf16x4){hh[4], hh[5], hh[6], hh[7]};
    *(bf16x4*)(Xl + idx)     = (bf16x4){ll[0], ll[1], ll[2], ll[3]};
    *(bf16x4*)(Xl + idx + 4) = (bf16x4){ll[4], ll[5], ll[6], ll[7]};
}

// cvt_qkv: grid (2048, 3) -> q,k,v
__global__ __launch_bounds__(256) void cvt_qkv(
    const float* __restrict__ q, const float* __restrict__ k,
    const float* __restrict__ v,
    short* __restrict__ qh, short* __restrict__ ql,
    short* __restrict__ kh, short* __restrict__ kl,
    short* __restrict__ vh, short* __restrict__ vl) {
    const float* X; short *Xh, *Xl;
    if (blockIdx.y == 0)      { X = q; Xh = qh; Xl = ql; }
    else if (blockIdx.y == 1) { X = k; Xh = kh; Xl = kl; }
    else                      { X = v; Xh = vh; Xl = vl; }
    cvt_body(X, Xh, Xl, ((size_t)blockIdx.x * 256 + threadIdx.x) * 8);
}

// cvt_w: grid (128, 4) -> w_q, w_k, w_v, w_o
__global__ __launch_bounds__(256) void cvt_w(
    const float* __restrict__ wq, const float* __restrict__ wk,
    const float* __restrict__ wv, const float* __restrict__ wo,
    short* __restrict__ qh, short* __restrict__ ql,
    short* __restrict__ kh, short* __restrict__ kl,
    short* __restrict__ vh, short* __restrict__ vl,
    short* __restrict__ oh, short* __restrict__ ol) {
    const float* X; short *Xh, *Xl;
    if (blockIdx.y == 0)      { X = wq; Xh = qh; Xl = ql; }
    else if (blockIdx.y == 1) { X = wk; Xh = kh; Xl = kl; }
    else if (blockIdx.y == 2) { X = wv; Xh = vh; Xl = vl; }
    else                      { X = wo; Xh = oh; Xl = ol; }
    cvt_body(X, Xh, Xl, ((size_t)blockIdx.x * 256 + threadIdx.x) * 8);
}

// ---------------------------------------------------------------------------
// stage_bf (verified)
// ---------------------------------------------------------------------------
__device__ __forceinline__ void stage_bf(const short* __restrict__ srcH,
                                         const short* __restrict__ srcL,
                                         short* Hh, short* Hl, int tid, int rows) {
#pragma unroll
    for (int p = 0; p < rows / 32; ++p) {
        int idx = tid + p * 256;
        int r = idx >> 3;
        int cc = idx & 7;
        int off = r * 64 + ((cc ^ (r & 7)) << 3);
        *(bf16x8*)(Hh + off) = *(const bf16x8*)(srcH + (size_t)r * 512 + cc * 8);
        *(bf16x8*)(Hl + off) = *(const bf16x8*)(srcL + (size_t)r * 512 + cc * 8);
    }
}

// ---------------------------------------------------------------------------
// gemm_bf: C[m][n] = sum_k A[m][k]*W[n][k], pre-converted hi/lo bf16 inputs.
// EPI 0: fp32 C.  EPI 1: head-major hi/lo (Q/K).  EPI 2: head-major V^T bf16.
// ---------------------------------------------------------------------------
template <int EPI>
__global__ __launch_bounds__(256) void gemm_bf(const short* __restrict__ Ah_g,
                                               const short* __restrict__ Al_g,
                                               const short* __restrict__ Wh_g,
                                               const short* __restrict__ Wl_g,
                                               float* __restrict__ C,
                                               short* __restrict__ Ch,
                                               short* __restrict__ Cl) {
    __shared__ __align__(16) short Ah[8192];
    __shared__ __align__(16) short Al[8192];
    __shared__ __align__(16) short Wh[4096];
    __shared__ __align__(16) short Wl[4096];

    const int tid = threadIdx.x;
    const int wave = tid >> 6;
    const int lane = tid & 63;
    const int lg = lane >> 4;
    const int lr = lane & 15;
    const int bm = blockIdx.x * 128;
    const int bn = blockIdx.y * 64;

    f32x4 acc[2][4];
#pragma unroll
    for (int s = 0; s < 2; ++s)
#pragma unroll
        for (int n = 0; n < 4; ++n) acc[s][n] = (f32x4){0.f, 0.f, 0.f, 0.f};

    for (int k0 = 0; k0 < 512; k0 += 64) {
        stage_bf(Ah_g + (size_t)bm * 512 + k0, Al_g + (size_t)bm * 512 + k0, Ah, Al, tid, 128);
        stage_bf(Wh_g + (size_t)bn * 512 + k0, Wl_g + (size_t)bn * 512 + k0, Wh, Wl, tid, 64);
        __syncthreads();

#pragma unroll
        for (int ks = 0; ks < 2; ++ks) {
            bf16x8 ah[2], al[2];
#pragma unroll
            for (int sub = 0; sub < 2; ++sub) {
                int r = wave * 32 + sub * 16 + lr;
                int off = r * 64 + (((ks * 4 + lg) ^ (r & 7)) << 3);
                ah[sub] = *(const bf16x8*)(Ah + off);
                al[sub] = *(const bf16x8*)(Al + off);
            }
#pragma unroll
            for (int nsub = 0; nsub < 4; ++nsub) {
                int r = nsub * 16 + lr;
                int off = r * 64 + (((ks * 4 + lg) ^ (r & 7)) << 3);
                bf16x8 wh = *(const bf16x8*)(Wh + off);
                bf16x8 wl = *(const bf16x8*)(Wl + off);
#pragma unroll
                for (int sub = 0; sub < 2; ++sub) {
                    acc[sub][nsub] = MFMA32(ah[sub], wh, acc[sub][nsub]);
                    acc[sub][nsub] = MFMA32(ah[sub], wl, acc[sub][nsub]);
                    acc[sub][nsub] = MFMA32(al[sub], wh, acc[sub][nsub]);
                }
            }
        }
        __syncthreads();
    }

    if (EPI == 2) {
#pragma unroll
        for (int sub = 0; sub < 2; ++sub)
#pragma unroll
            for (int nsub = 0; nsub < 4; ++nsub)
#pragma unroll
                for (int rr = 0; rr < 4; ++rr) {
                    int rloc = wave * 32 + sub * 16 + lg * 4 + rr;
                    int cloc = nsub * 16 + lr;
                    short bv = (short)f2bf(acc[sub][nsub][rr]);
                    if (rloc < 64) Ah[rloc * 66 + cloc] = bv;
                    else           Al[(rloc - 64) * 66 + cloc] = bv;
                }
        __syncthreads();
        const int dk = tid >> 2;
        const int j0l = (tid & 3) * 32;
        const short* src = (j0l < 64) ? Ah : Al;
        const int jb = j0l & 63;
        const int h = bn >> 6;
        const int bq = bm >> 11;
        short* dst = Ch + ((size_t)((bq * 8 + h) * 64 + dk)) * 2048 + (bm & 2047) + j0l;
#pragma unroll
        for (int qq = 0; qq < 4; ++qq) {
            bf16x8 o;
#pragma unroll
            for (int e = 0; e < 8; ++e)
                o[e] = src[(jb + qq * 8 + e) * 66 + dk];
            *(bf16x8*)(dst + qq * 8) = o;
        }
        return;
    }

#pragma unroll
    for (int sub = 0; sub < 2; ++sub)
#pragma unroll
        for (int nsub = 0; nsub < 4; ++nsub)
#pragma unroll
            for (int rr = 0; rr < 4; ++rr) {
                int row = bm + wave * 32 + sub * 16 + lg * 4 + rr;
                int col = bn + nsub * 16 + lr;
                float a = acc[sub][nsub][rr];
                if (EPI == 0) {
                    C[(size_t)row * 512 + col] = a;
                } else {
                    unsigned short hb = f2bf(a);
                    size_t off = (((size_t)(row >> 11) * 8 + (col >> 6)) * 2048 +
                                  (row & 2047)) * 64 + (col & 63);
                    Ch[off] = (short)hb;
                    Cl[off] = (short)f2bf(a - bf2f(hb));
                }
            }
}

// ---------------------------------------------------------------------------
// mask_pack (unchanged)
// ---------------------------------------------------------------------------
__global__ __launch_bounds__(256) void mask_pack(const int* __restrict__ mask,
                                                 unsigned long long* __restrict__ pk) {
    const int row = blockIdx.x;
    const int tid = threadIdx.x;
    const int* mrow = mask + (size_t)row * 2048;
#pragma unroll
    for (int p = 0; p < 8; ++p) {
        int j = p * 256 + tid;
        unsigned long long bal = __ballot(mrow[j] != 0);
        if ((tid & 63) == 0) pk[(size_t)row * 32 + p * 4 + (tid >> 6)] = bal;
    }
}

// ---------------------------------------------------------------------------
// Fused attention: round-17/20 verified kernel (341-343 us), verbatim.
// ---------------------------------------------------------------------------
__global__ __launch_bounds__(256, 3) void fused_attn(
    const short* __restrict__ Qh_g, const short* __restrict__ Ql_g,
    const short* __restrict__ Kh_g, const short* __restrict__ Kl_g,
    const short* __restrict__ Vt_g, const unsigned long long* __restrict__ pk,
    float* __restrict__ P, short* __restrict__ Aho, short* __restrict__ Alo) {
    __shared__ __align__(16) short Kbuf[2][2][4096];
    __shared__ __align__(16) short Wt[4096];

    const int tid = threadIdx.x;
    const int wave = tid >> 6;
    const int lane = tid & 63;
    const int lg = lane >> 4;
    const int lr = lane & 15;

    const int wgid = blockIdx.y * 32 + blockIdx.x;
    const int xcd = wgid & 7;
    const int slot = wgid >> 3;
    const int bh = xcd * 4 + (slot & 3);
    const int i0 = (slot >> 2) * 64;
    const int b = bh >> 3;

    bf16x8 qh[2], ql[2];
    {
        const size_t qbase = ((size_t)bh * 2048 + i0 + wave * 16 + lr) * 64;
#pragma unroll
        for (int ks = 0; ks < 2; ++ks) {
            qh[ks] = *(const bf16x8*)(Qh_g + qbase + (ks * 4 + lg) * 8);
            ql[ks] = *(const bf16x8*)(Ql_g + qbase + (ks * 4 + lg) * 8);
        }
    }

    const int o0 = tid * 16;
    const int o1 = 4096 + tid * 16;
    const int s0 = o0 ^ (((o0 >> 7) & 7) << 4);
    const int s1 = o1 ^ (((o1 >> 7) & 7) << 4);

    bf16x8 Rh0, Rh1, Rl0, Rl1;
#define LOADKH(t)                                                           \
    {                                                                       \
        const short* bKh = Kh_g + ((size_t)bh * 2048 + (t) * 64) * 64;      \
        Rh0 = *(const bf16x8*)(bKh + (o0 >> 1));                            \
        Rh1 = *(const bf16x8*)(bKh + (o1 >> 1));                            \
    }
#define WRITEKH(cur)                                                        \
    {                                                                       \
        *(bf16x8*)(&Kbuf[cur][0][0] + (s0 >> 1)) = Rh0;                     \
        *(bf16x8*)(&Kbuf[cur][0][0] + (s1 >> 1)) = Rh1;                     \
    }
#define LOADK(t)                                                            \
    {                                                                       \
        const short* bKh = Kh_g + ((size_t)bh * 2048 + (t) * 64) * 64;      \
        const short* bKl = Kl_g + ((size_t)bh * 2048 + (t) * 64) * 64;      \
        Rh0 = *(const bf16x8*)(bKh + (o0 >> 1));                            \
        Rh1 = *(const bf16x8*)(bKh + (o1 >> 1));                            \
        Rl0 = *(const bf16x8*)(bKl + (o0 >> 1));                            \
        Rl1 = *(const bf16x8*)(bKl + (o1 >> 1));                            \
    }
#define WRITEK(cur)                                                         \
    {                                                                       \
        *(bf16x8*)(&Kbuf[cur][0][0] + (s0 >> 1)) = Rh0;                     \
        *(bf16x8*)(&Kbuf[cur][0][0] + (s1 >> 1)) = Rh1;                     \
        *(bf16x8*)(&Kbuf[cur][1][0] + (s0 >> 1)) = Rl0;                     \
        *(bf16x8*)(&Kbuf[cur][1][0] + (s1 >> 1)) = Rl1;                     \
    }

    const size_t pkrow = (size_t)b * 2048 + i0 + wave * 16 + lg * 4;

    // ===== sweep 1 (lite): l = sum_j exp(s_hi) per row, no max shift =====
    float l_[4] = {0.f, 0.f, 0.f, 0.f};

    LOADKH(0);
    for (int t = 0; t < 32; ++t) {
        const int cur = t & 1;
        WRITEKH(cur);
        if (t < 31) LOADKH(t + 1);
        unsigned long long pkv[4];
#pragma unroll
        for (int rr = 0; rr < 4; ++rr) pkv[rr] = pk[(pkrow + rr) * 32 + t];
        __syncthreads();

        const short* KH = &Kbuf[cur][0][0];
#pragma unroll
        for (int jt = 0; jt < 4; ++jt) {
            f32x4 s = (f32x4){0.f, 0.f, 0.f, 0.f};
            int r = jt * 16 + lr;
#pragma unroll
            for (int ks = 0; ks < 2; ++ks) {
                int off = (r * 128 + (ks * 4 + lg) * 16) ^ ((r & 7) << 4);
                bf16x8 kh = *(const bf16x8*)(KH + (off >> 1));
                s = MFMA32(qh[ks], kh, s);
            }
#pragma unroll
            for (int rr = 0; rr < 4; ++rr) {
                bool mk = (pkv[rr] >> (jt * 16 + lr)) & 1ull;
                l_[rr] += mk ? 0.f : __expf(s[rr] * 0.125f);
            }
        }
    }

    // cross-lane sum of l over the 16 lr lanes
#pragma unroll
    for (int rr = 0; rr < 4; ++rr) {
        float l = l_[rr];
#pragma unroll
        for (int d = 1; d < 16; d <<= 1) l += __shfl_xor(l, d);
        l_[rr] = l;
    }

    float invl[4];
#pragma unroll
    for (int rr = 0; rr < 4; ++rr) invl[rr] = 1.0f / fmaxf(l_[rr], 1e-37f);

    // ====================== sweep 2: weights + P + PV ======================
    f32x4 Oa[4];
#pragma unroll
    for (int dt = 0; dt < 4; ++dt) Oa[dt] = (f32x4){0.f, 0.f, 0.f, 0.f};

    LOADK(0);
    for (int t = 0; t < 32; ++t) {
        const int cur = t & 1;
        WRITEK(cur);
        if (t < 31) LOADK(t + 1);
        unsigned long long pkv[4];
#pragma unroll
        for (int rr = 0; rr < 4; ++rr) pkv[rr] = pk[(pkrow + rr) * 32 + t];
        bf16x8 vf[4][2];
#pragma unroll
        for (int dt = 0; dt < 4; ++dt)
#pragma unroll
            for (int ks2 = 0; ks2 < 2; ++ks2)
                vf[dt][ks2] = *(const bf16x8*)(Vt_g +
                    ((size_t)(bh * 64 + dt * 16 + lr)) * 2048 + t * 64 + (ks2 * 4 + lg) * 8);
        __syncthreads();

        const short* KH = &Kbuf[cur][0][0];
        const short* KL = &Kbuf[cur][1][0];
#pragma unroll
        for (int jt = 0; jt < 4; ++jt) {
            f32x4 s = (f32x4){0.f, 0.f, 0.f, 0.f};
            int r = jt * 16 + lr;
#pragma unroll
            for (int ks = 0; ks < 2; ++ks) {
                int off = (r * 128 + (ks * 4 + lg) * 16) ^ ((r & 7) << 4);
                bf16x8 kh = *(const bf16x8*)(KH + (off >> 1));
                bf16x8 kl = *(const bf16x8*)(KL + (off >> 1));
                s = MFMA32(qh[ks], kh, s);
                s = MFMA32(qh[ks], kl, s);
                s = MFMA32(ql[ks], kh, s);
            }
#pragma unroll
            for (int rr = 0; rr < 4; ++rr) {
                bool mk = (pkv[rr] >> (jt * 16 + lr)) & 1ull;
                float w = mk ? 0.f : __expf(s[rr] * 0.125f) * invl[rr];
                int rw = wave * 16 + lg * 4 + rr;
                int wo = rw * 64 + (((jt * 2 + (lr >> 3)) ^ (rw & 7)) << 3) + (lr & 7);
                Wt[wo] = (short)f2bf(w);
            }
        }

        // P write (wave-own rows): bf16 Wt -> fp32, coalesced 16B stores
        {
            int rp = wave * 16 + (lane >> 2);
            int c2 = (lane & 3) * 2;
            int po0 = rp * 64 + (((c2 + 0) ^ (rp & 7)) << 3);
            int po1 = rp * 64 + (((c2 + 1) ^ (rp & 7)) << 3);
            bf16x8 wa = *(const bf16x8*)(Wt + po0);
            bf16x8 wb = *(const bf16x8*)(Wt + po1);
            float* Prow = P + ((size_t)bh * 2048 + i0 + rp) * 2048 + t * 64 + (lane & 3) * 16;
#pragma unroll
            for (int q = 0; q < 2; ++q) {
                f32x4 oA = {bf2f((unsigned short)wa[q * 4 + 0]), bf2f((unsigned short)wa[q * 4 + 1]),
                            bf2f((unsigned short)wa[q * 4 + 2]), bf2f((unsigned short)wa[q * 4 + 3])};
                f32x4 oB = {bf2f((unsigned short)wb[q * 4 + 0]), bf2f((unsigned short)wb[q * 4 + 1]),
                            bf2f((unsigned short)wb[q * 4 + 2]), bf2f((unsigned short)wb[q * 4 + 3])};
                *(f32x4*)(Prow + q * 4) = oA;
                *(f32x4*)(Prow + 8 + q * 4) = oB;
            }
        }

        // PV: A-frag = wave's own Wt rows, B-frag = V^T registers
        bf16x8 aw[2];
#pragma unroll
        for (int ks2 = 0; ks2 < 2; ++ks2) {
            int ra = wave * 16 + lr;
            int ao = ra * 64 + (((ks2 * 4 + lg) ^ (ra & 7)) << 3);
            aw[ks2] = *(const bf16x8*)(Wt + ao);
        }
#pragma unroll
        for (int dt = 0; dt < 4; ++dt)
#pragma unroll
            for (int ks2 = 0; ks2 < 2; ++ks2)
                Oa[dt] = MFMA32(aw[ks2], vf[dt][ks2], Oa[dt]);
    }

    // context out as hi/lo bf16 rowmajor [8192][512]
    {
        const int h = bh & 7;
#pragma unroll
        for (int dt = 0; dt < 4; ++dt)
#pragma unroll
            for (int rr = 0; rr < 4; ++rr) {
                int gi = i0 + wave * 16 + lg * 4 + rr;
                size_t off = ((size_t)(b * 2048 + gi)) * 512 + h * 64 + dt * 16 + lr;
                float a = Oa[dt][rr];
                unsigned short hb = f2bf(a);
                Aho[off] = (short)hb;
                Alo[off] = (short)f2bf(a - bf2f(hb));
            }
    }
#undef LOADKH
#undef WRITEKH
#undef LOADK
#undef WRITEK
}

// ---------------------------------------------------------------------------
extern "C" void kernel_launch(void* const* d_in, const int* in_sizes, int n_in,
                              void* d_out, int out_size, void* d_ws, size_t ws_size,
                              hipStream_t stream) {
    const float* q   = (const float*)d_in[0];
    const float* k   = (const float*)d_in[1];
    const float* v   = (const float*)d_in[2];
    const int*   msk = (const int*)d_in[3];
    const float* w_q = (const float*)d_in[4];
    const float* w_k = (const float*)d_in[5];
    const float* w_v = (const float*)d_in[6];
    const float* w_o = (const float*)d_in[7];

    float* out = (float*)d_out;                 // [B,S,D]
    float* P   = out + (size_t)B_ * S_ * D_;    // [B,H,S,S]

    // ws layout (~96 MB)
    short* qh = (short*)d_ws;                   // [8192][512] bf16 hi (later context hi)
    short* ql = qh + (size_t)4194304;
    short* kh = ql + (size_t)4194304;
    short* kl = kh + (size_t)4194304;
    short* vh = kl + (size_t)4194304;
    short* vl = vh + (size_t)4194304;
    short* Qh = vl + (size_t)4194304;           // head-major
    short* Ql = Qh + (size_t)4194304;
    short* Kh = Ql + (size_t)4194304;
    short* Kl = Kh + (size_t)4194304;
    short* Vt = Kl + (size_t)4194304;           // [32][64][2048] bf16 (V^T)
    unsigned long long* pk = (unsigned long long*)(Vt + (size_t)4194304);
    short* wqh = (short*)(pk + (size_t)262144); // 512x512 each
    short* wql = wqh + (size_t)262144;
    short* wkh = wql + (size_t)262144;
    short* wkl = wkh + (size_t)262144;
    short* wvh = wkl + (size_t)262144;
    short* wvl = wvh + (size_t)262144;
    short* woh = wvl + (size_t)262144;
    short* wol = woh + (size_t)262144;

    dim3 blk(256);
    dim3 gproj(M_ / 128, D_ / 64);              // (64, 8)

    hipLaunchKernelGGL(cvt_qkv, dim3(2048, 3), blk, 0, stream,
                       q, k, v, qh, ql, kh, kl, vh, vl);
    hipLaunchKernelGGL(cvt_w, dim3(128, 4), blk, 0, stream,
                       w_q, w_k, w_v, w_o, wqh, wql, wkh, wkl, wvh, wvl, woh, wol);

    hipLaunchKernelGGL((gemm_bf<1>), gproj, blk, 0, stream, qh, ql, wqh, wql,
                       (float*)nullptr, Qh, Ql);
    hipLaunchKernelGGL((gemm_bf<1>), gproj, blk, 0, stream, kh, kl, wkh, wkl,
                       (float*)nullptr, Kh, Kl);
    hipLaunchKernelGGL((gemm_bf<2>), gproj, blk, 0, stream, vh, vl, wvh, wvl,
                       (float*)nullptr, Vt, (short*)nullptr);

    hipLaunchKernelGGL(mask_pack, dim3(M_), blk, 0, stream, msk, pk);

    // context written into qh/ql (dead after Q-gemm) as hi/lo bf16
    hipLaunchKernelGGL(fused_attn, dim3(32, 32), blk, 0, stream,
                       Qh, Ql, Kh, Kl, Vt, pk, P, qh, ql);

    hipLaunchKernelGGL((gemm_bf<0>), gproj, blk, 0, stream, qh, ql, woh, wol,
                       out, (short*)nullptr, (short*)nullptr);
}

// Round 23
// 388.584 us; speedup vs baseline: 2.3704x; 1.1584x over previous
//
#include <hip/hip_runtime.h>
#include <hip/hip_bf16.h>
#include <cstdint>

constexpr int B_ = 4;
constexpr int S_ = 2048;
constexpr int D_ = 512;
constexpr int H_ = 8;
constexpr int DK_ = 64;
constexpr int M_ = B_ * S_;

typedef __attribute__((ext_vector_type(8))) short bf16x8;
typedef __attribute__((ext_vector_type(4))) short bf16x4;
typedef __attribute__((ext_vector_type(4))) float f32x4;

__device__ __forceinline__ unsigned short f2bf(float x) {
    unsigned u = __float_as_uint(x);
    return (unsigned short)((u + 0x7fffu + ((u >> 16) & 1u)) >> 16);
}
__device__ __forceinline__ float bf2f(unsigned short h) {
    return __uint_as_float(((unsigned)h) << 16);
}

#define MFMA32(a, b, c) __builtin_amdgcn_mfma_f32_16x16x32_bf16(a, b, c, 0, 0, 0)

// ---------------------------------------------------------------------------
// cvt body (verified): fp32 -> hi/lo bf16 at linear idx
// ---------------------------------------------------------------------------
__device__ __forceinline__ void cvt_body(const float* __restrict__ X,
                                         short* __restrict__ Xh,
                                         short* __restrict__ Xl, size_t idx) {
    float4 v0 = *reinterpret_cast<const float4*>(X + idx);
    float4 v1 = *reinterpret_cast<const float4*>(X + idx + 4);
    float f[8] = {v0.x, v0.y, v0.z, v0.w, v1.x, v1.y, v1.z, v1.w};
    short hh[8], ll[8];
#pragma unroll
    for (int e = 0; e < 8; ++e) {
        unsigned short hb = f2bf(f[e]);
        hh[e] = (short)hb;
        ll[e] = (short)f2bf(f[e] - bf2f(hb));
    }
    *(bf16x4*)(Xh + idx)     = (bf16x4){hh[0], hh[1], hh[2], hh[3]};
    *(bf16x4*)(Xh + idx + 4) = (bf16x4){hh[4], hh[5], hh[6], hh[7]};
    *(bf16x4*)(Xl + idx)     = (bf16x4){ll[0], ll[1], ll[2], ll[3]};
    *(bf16x4*)(Xl + idx + 4) = (bf16x4){ll[4], ll[5], ll[6], ll[7]};
}

// cvt_qkv: grid (2048, 3) -> q,k,v
__global__ __launch_bounds__(256) void cvt_qkv(
    const float* __restrict__ q, const float* __restrict__ k,
    const float* __restrict__ v,
    short* __restrict__ qh, short* __restrict__ ql,
    short* __restrict__ kh, short* __restrict__ kl,
    short* __restrict__ vh, short* __restrict__ vl) {
    const float* X; short *Xh, *Xl;
    if (blockIdx.y == 0)      { X = q; Xh = qh; Xl = ql; }
    else if (blockIdx.y == 1) { X = k; Xh = kh; Xl = kl; }
    else                      { X = v; Xh = vh; Xl = vl; }
    cvt_body(X, Xh, Xl, ((size_t)blockIdx.x * 256 + threadIdx.x) * 8);
}

// cvt_w: grid (128, 4) -> w_q, w_k, w_v, w_o
__global__ __launch_bounds__(256) void cvt_w(
    const float* __restrict__ wq, const float* __restrict__ wk,
    const float* __restrict__ wv, const float* __restrict__ wo,
    short* __restrict__ qh, short* __restrict__ ql,
    short* __restrict__ kh, short* __restrict__ kl,
    short* __restrict__ vh, short* __restrict__ vl,
    short* __restrict__ oh, short* __restrict__ ol) {
    const float* X; short *Xh, *Xl;
    if (blockIdx.y == 0)      { X = wq; Xh = qh; Xl = ql; }
    else if (blockIdx.y == 1) { X = wk; Xh = kh; Xl = kl; }
    else if (blockIdx.y == 2) { X = wv; Xh = vh; Xl = vl; }
    else                      { X = wo; Xh = oh; Xl = ol; }
    cvt_body(X, Xh, Xl, ((size_t)blockIdx.x * 256 + threadIdx.x) * 8);
}

// ---------------------------------------------------------------------------
// stage_bf (verified)
// ---------------------------------------------------------------------------
__device__ __forceinline__ void stage_bf(const short* __restrict__ srcH,
                                         const short* __restrict__ srcL,
                                         short* Hh, short* Hl, int tid, int rows) {
#pragma unroll
    for (int p = 0; p < rows / 32; ++p) {
        int idx = tid + p * 256;
        int r = idx >> 3;
        int cc = idx & 7;
        int off = r * 64 + ((cc ^ (r & 7)) << 3);
        *(bf16x8*)(Hh + off) = *(const bf16x8*)(srcH + (size_t)r * 512 + cc * 8);
        *(bf16x8*)(Hl + off) = *(const bf16x8*)(srcL + (size_t)r * 512 + cc * 8);
    }
}

// ---------------------------------------------------------------------------
// gemm_bf: C[m][n] = sum_k A[m][k]*W[n][k], pre-converted hi/lo bf16 inputs.
// EPI 0: fp32 C.  EPI 1: head-major hi/lo (Q/K).  EPI 2: head-major V^T bf16.
// ---------------------------------------------------------------------------
template <int EPI>
__global__ __launch_bounds__(256) void gemm_bf(const short* __restrict__ Ah_g,
                                               const short* __restrict__ Al_g,
                                               const short* __restrict__ Wh_g,
                                               const short* __restrict__ Wl_g,
                                               float* __restrict__ C,
                                               short* __restrict__ Ch,
                                               short* __restrict__ Cl) {
    __shared__ __align__(16) short Ah[8192];
    __shared__ __align__(16) short Al[8192];
    __shared__ __align__(16) short Wh[4096];
    __shared__ __align__(16) short Wl[4096];

    const int tid = threadIdx.x;
    const int wave = tid >> 6;
    const int lane = tid & 63;
    const int lg = lane >> 4;
    const int lr = lane & 15;
    const int bm = blockIdx.x * 128;
    const int bn = blockIdx.y * 64;

    f32x4 acc[2][4];
#pragma unroll
    for (int s = 0; s < 2; ++s)
#pragma unroll
        for (int n = 0; n < 4; ++n) acc[s][n] = (f32x4){0.f, 0.f, 0.f, 0.f};

    for (int k0 = 0; k0 < 512; k0 += 64) {
        stage_bf(Ah_g + (size_t)bm * 512 + k0, Al_g + (size_t)bm * 512 + k0, Ah, Al, tid, 128);
        stage_bf(Wh_g + (size_t)bn * 512 + k0, Wl_g + (size_t)bn * 512 + k0, Wh, Wl, tid, 64);
        __syncthreads();

#pragma unroll
        for (int ks = 0; ks < 2; ++ks) {
            bf16x8 ah[2], al[2];
#pragma unroll
            for (int sub = 0; sub < 2; ++sub) {
                int r = wave * 32 + sub * 16 + lr;
                int off = r * 64 + (((ks * 4 + lg) ^ (r & 7)) << 3);
                ah[sub] = *(const bf16x8*)(Ah + off);
                al[sub] = *(const bf16x8*)(Al + off);
            }
#pragma unroll
            for (int nsub = 0; nsub < 4; ++nsub) {
                int r = nsub * 16 + lr;
                int off = r * 64 + (((ks * 4 + lg) ^ (r & 7)) << 3);
                bf16x8 wh = *(const bf16x8*)(Wh + off);
                bf16x8 wl = *(const bf16x8*)(Wl + off);
#pragma unroll
                for (int sub = 0; sub < 2; ++sub) {
                    acc[sub][nsub] = MFMA32(ah[sub], wh, acc[sub][nsub]);
                    acc[sub][nsub] = MFMA32(ah[sub], wl, acc[sub][nsub]);
                    acc[sub][nsub] = MFMA32(al[sub], wh, acc[sub][nsub]);
                }
            }
        }
        __syncthreads();
    }

    if (EPI == 2) {
#pragma unroll
        for (int sub = 0; sub < 2; ++sub)
#pragma unroll
            for (int nsub = 0; nsub < 4; ++nsub)
#pragma unroll
                for (int rr = 0; rr < 4; ++rr) {
                    int rloc = wave * 32 + sub * 16 + lg * 4 + rr;
                    int cloc = nsub * 16 + lr;
                    short bv = (short)f2bf(acc[sub][nsub][rr]);
                    if (rloc < 64) Ah[rloc * 66 + cloc] = bv;
                    else           Al[(rloc - 64) * 66 + cloc] = bv;
                }
        __syncthreads();
        const int dk = tid >> 2;
        const int j0l = (tid & 3) * 32;
        const short* src = (j0l < 64) ? Ah : Al;
        const int jb = j0l & 63;
        const int h = bn >> 6;
        const int bq = bm >> 11;
        short* dst = Ch + ((size_t)((bq * 8 + h) * 64 + dk)) * 2048 + (bm & 2047) + j0l;
#pragma unroll
        for (int qq = 0; qq < 4; ++qq) {
            bf16x8 o;
#pragma unroll
            for (int e = 0; e < 8; ++e)
                o[e] = src[(jb + qq * 8 + e) * 66 + dk];
            *(bf16x8*)(dst + qq * 8) = o;
        }
        return;
    }

#pragma unroll
    for (int sub = 0; sub < 2; ++sub)
#pragma unroll
        for (int nsub = 0; nsub < 4; ++nsub)
#pragma unroll
            for (int rr = 0; rr < 4; ++rr) {
                int row = bm + wave * 32 + sub * 16 + lg * 4 + rr;
                int col = bn + nsub * 16 + lr;
                float a = acc[sub][nsub][rr];
                if (EPI == 0) {
                    C[(size_t)row * 512 + col] = a;
                } else {
                    unsigned short hb = f2bf(a);
                    size_t off = (((size_t)(row >> 11) * 8 + (col >> 6)) * 2048 +
                                  (row & 2047)) * 64 + (col & 63);
                    Ch[off] = (short)hb;
                    Cl[off] = (short)f2bf(a - bf2f(hb));
                }
            }
}

// ---------------------------------------------------------------------------
// mask_pack (unchanged)
// ---------------------------------------------------------------------------
__global__ __launch_bounds__(256) void mask_pack(const int* __restrict__ mask,
                                                 unsigned long long* __restrict__ pk) {
    const int row = blockIdx.x;
    const int tid = threadIdx.x;
    const int* mrow = mask + (size_t)row * 2048;
#pragma unroll
    for (int p = 0; p < 8; ++p) {
        int j = p * 256 + tid;
        unsigned long long bal = __ballot(mrow[j] != 0);
        if ((tid & 63) == 0) pk[(size_t)row * 32 + p * 4 + (tid >> 6)] = bal;
    }
}

// ---------------------------------------------------------------------------
// Fused attention v11 = round-22 kernel with V staged in LDS (dbuf, swizzled)
// in sweep 2: removes the 4x-redundant scattered per-wave V loads (the vf
// indexing had no wave term -> all 4 waves issued identical 16B x 64-lane
// scatters). Staging: 2 semi-contiguous loads/iter; fragment reads use the
// verified K-style XOR pattern. LDS 40 -> 56 KB.
// ---------------------------------------------------------------------------
__global__ __launch_bounds__(256, 2) void fused_attn(
    const short* __restrict__ Qh_g, const short* __restrict__ Ql_g,
    const short* __restrict__ Kh_g, const short* __restrict__ Kl_g,
    const short* __restrict__ Vt_g, const unsigned long long* __restrict__ pk,
    float* __restrict__ P, short* __restrict__ Aho, short* __restrict__ Alo) {
    __shared__ __align__(16) short Kbuf[2][2][4096];
    __shared__ __align__(16) short Vbuf[2][4096];
    __shared__ __align__(16) short Wt[4096];

    const int tid = threadIdx.x;
    const int wave = tid >> 6;
    const int lane = tid & 63;
    const int lg = lane >> 4;
    const int lr = lane & 15;

    const int wgid = blockIdx.y * 32 + blockIdx.x;
    const int xcd = wgid & 7;
    const int slot = wgid >> 3;
    const int bh = xcd * 4 + (slot & 3);
    const int i0 = (slot >> 2) * 64;
    const int b = bh >> 3;

    bf16x8 qh[2], ql[2];
    {
        const size_t qbase = ((size_t)bh * 2048 + i0 + wave * 16 + lr) * 64;
#pragma unroll
        for (int ks = 0; ks < 2; ++ks) {
            qh[ks] = *(const bf16x8*)(Qh_g + qbase + (ks * 4 + lg) * 8);
            ql[ks] = *(const bf16x8*)(Ql_g + qbase + (ks * 4 + lg) * 8);
        }
    }

    const int o0 = tid * 16;
    const int o1 = 4096 + tid * 16;
    const int s0 = o0 ^ (((o0 >> 7) & 7) << 4);
    const int s1 = o1 ^ (((o1 >> 7) & 7) << 4);

    // V staging geometry: idx = tid + p*256 in [0,512); r = idx>>3, cc = idx&7
    const int vr0 = tid >> 3, vc0 = tid & 7;
    const int vr1 = (tid + 256) >> 3, vc1 = (tid + 256) & 7;
    const int vs0 = vr0 * 64 + ((vc0 ^ (vr0 & 7)) << 3);
    const int vs1 = vr1 * 64 + ((vc1 ^ (vr1 & 7)) << 3);
    const short* Vbase = Vt_g + (size_t)bh * 64 * 2048;

    bf16x8 Rh0, Rh1, Rl0, Rl1, Rv0, Rv1;
#define LOADKH(t)                                                           \
    {                                                                       \
        const short* bKh = Kh_g + ((size_t)bh * 2048 + (t) * 64) * 64;      \
        Rh0 = *(const bf16x8*)(bKh + (o0 >> 1));                            \
        Rh1 = *(const bf16x8*)(bKh + (o1 >> 1));                            \
    }
#define WRITEKH(cur)                                                        \
    {                                                                       \
        *(bf16x8*)(&Kbuf[cur][0][0] + (s0 >> 1)) = Rh0;                     \
        *(bf16x8*)(&Kbuf[cur][0][0] + (s1 >> 1)) = Rh1;                     \
    }
#define LOADK(t)                                                            \
    {                                                                       \
        const short* bKh = Kh_g + ((size_t)bh * 2048 + (t) * 64) * 64;      \
        const short* bKl = Kl_g + ((size_t)bh * 2048 + (t) * 64) * 64;      \
        Rh0 = *(const bf16x8*)(bKh + (o0 >> 1));                            \
        Rh1 = *(const bf16x8*)(bKh + (o1 >> 1));                            \
        Rl0 = *(const bf16x8*)(bKl + (o0 >> 1));                            \
        Rl1 = *(const bf16x8*)(bKl + (o1 >> 1));                            \
    }
#define WRITEK(cur)                                                         \
    {                                                                       \
        *(bf16x8*)(&Kbuf[cur][0][0] + (s0 >> 1)) = Rh0;                     \
        *(bf16x8*)(&Kbuf[cur][0][0] + (s1 >> 1)) = Rh1;                     \
        *(bf16x8*)(&Kbuf[cur][1][0] + (s0 >> 1)) = Rl0;                     \
        *(bf16x8*)(&Kbuf[cur][1][0] + (s1 >> 1)) = Rl1;                     \
    }
#define LOADV(t)                                                            \
    {                                                                       \
        const short* bV = Vbase + (t) * 64;                                 \
        Rv0 = *(const bf16x8*)(bV + (size_t)vr0 * 2048 + vc0 * 8);          \
        Rv1 = *(const bf16x8*)(bV + (size_t)vr1 * 2048 + vc1 * 8);          \
    }
#define WRITEV(cur)                                                         \
    {                                                                       \
        *(bf16x8*)(&Vbuf[cur][0] + vs0) = Rv0;                              \
        *(bf16x8*)(&Vbuf[cur][0] + vs1) = Rv1;                              \
    }

    const size_t pkrow = (size_t)b * 2048 + i0 + wave * 16 + lg * 4;

    // ===== sweep 1 (lite): l = sum_j exp(s_hi) per row, no max shift =====
    float l_[4] = {0.f, 0.f, 0.f, 0.f};

    LOADKH(0);
    for (int t = 0; t < 32; ++t) {
        const int cur = t & 1;
        WRITEKH(cur);
        if (t < 31) LOADKH(t + 1);
        unsigned long long pkv[4];
#pragma unroll
        for (int rr = 0; rr < 4; ++rr) pkv[rr] = pk[(pkrow + rr) * 32 + t];
        __syncthreads();

        const short* KH = &Kbuf[cur][0][0];
#pragma unroll
        for (int jt = 0; jt < 4; ++jt) {
            f32x4 s = (f32x4){0.f, 0.f, 0.f, 0.f};
            int r = jt * 16 + lr;
#pragma unroll
            for (int ks = 0; ks < 2; ++ks) {
                int off = (r * 128 + (ks * 4 + lg) * 16) ^ ((r & 7) << 4);
                bf16x8 kh = *(const bf16x8*)(KH + (off >> 1));
                s = MFMA32(qh[ks], kh, s);
            }
#pragma unroll
            for (int rr = 0; rr < 4; ++rr) {
                bool mk = (pkv[rr] >> (jt * 16 + lr)) & 1ull;
                l_[rr] += mk ? 0.f : __expf(s[rr] * 0.125f);
            }
        }
    }

    // cross-lane sum of l over the 16 lr lanes
#pragma unroll
    for (int rr = 0; rr < 4; ++rr) {
        float l = l_[rr];
#pragma unroll
        for (int d = 1; d < 16; d <<= 1) l += __shfl_xor(l, d);
        l_[rr] = l;
    }

    float invl[4];
#pragma unroll
    for (int rr = 0; rr < 4; ++rr) invl[rr] = 1.0f / fmaxf(l_[rr], 1e-37f);

    // ====================== sweep 2: weights + P + PV ======================
    f32x4 Oa[4];
#pragma unroll
    for (int dt = 0; dt < 4; ++dt) Oa[dt] = (f32x4){0.f, 0.f, 0.f, 0.f};

    LOADK(0);
    LOADV(0);
    for (int t = 0; t < 32; ++t) {
        const int cur = t & 1;
        WRITEK(cur);
        WRITEV(cur);
        if (t < 31) { LOADK(t + 1); LOADV(t + 1); }
        unsigned long long pkv[4];
#pragma unroll
        for (int rr = 0; rr < 4; ++rr) pkv[rr] = pk[(pkrow + rr) * 32 + t];
        __syncthreads();

        const short* KH = &Kbuf[cur][0][0];
        const short* KL = &Kbuf[cur][1][0];
#pragma unroll
        for (int jt = 0; jt < 4; ++jt) {
            f32x4 s = (f32x4){0.f, 0.f, 0.f, 0.f};
            int r = jt * 16 + lr;
#pragma unroll
            for (int ks = 0; ks < 2; ++ks) {
                int off = (r * 128 + (ks * 4 + lg) * 16) ^ ((r & 7) << 4);
                bf16x8 kh = *(const bf16x8*)(KH + (off >> 1));
                bf16x8 kl = *(const bf16x8*)(KL + (off >> 1));
                s = MFMA32(qh[ks], kh, s);
                s = MFMA32(qh[ks], kl, s);
                s = MFMA32(ql[ks], kh, s);
            }
#pragma unroll
            for (int rr = 0; rr < 4; ++rr) {
                bool mk = (pkv[rr] >> (jt * 16 + lr)) & 1ull;
                float w = mk ? 0.f : __expf(s[rr] * 0.125f) * invl[rr];
                int rw = wave * 16 + lg * 4 + rr;
                int wo = rw * 64 + (((jt * 2 + (lr >> 3)) ^ (rw & 7)) << 3) + (lr & 7);
                Wt[wo] = (short)f2bf(w);
            }
        }

        // P write (wave-own rows): bf16 Wt -> fp32, coalesced 16B stores
        {
            int rp = wave * 16 + (lane >> 2);
            int c2 = (lane & 3) * 2;
            int po0 = rp * 64 + (((c2 + 0) ^ (rp & 7)) << 3);
            int po1 = rp * 64 + (((c2 + 1) ^ (rp & 7)) << 3);
            bf16x8 wa = *(const bf16x8*)(Wt + po0);
            bf16x8 wb = *(const bf16x8*)(Wt + po1);
            float* Prow = P + ((size_t)bh * 2048 + i0 + rp) * 2048 + t * 64 + (lane & 3) * 16;
#pragma unroll
            for (int q = 0; q < 2; ++q) {
                f32x4 oA = {bf2f((unsigned short)wa[q * 4 + 0]), bf2f((unsigned short)wa[q * 4 + 1]),
                            bf2f((unsigned short)wa[q * 4 + 2]), bf2f((unsigned short)wa[q * 4 + 3])};
                f32x4 oB = {bf2f((unsigned short)wb[q * 4 + 0]), bf2f((unsigned short)wb[q * 4 + 1]),
                            bf2f((unsigned short)wb[q * 4 + 2]), bf2f((unsigned short)wb[q * 4 + 3])};
                *(f32x4*)(Prow + q * 4) = oA;
                *(f32x4*)(Prow + 8 + q * 4) = oB;
            }
        }

        // PV: A-frag = wave's own Wt rows, B-frag = V tile from LDS (shared)
        bf16x8 aw[2];
#pragma unroll
        for (int ks2 = 0; ks2 < 2; ++ks2) {
            int ra = wave * 16 + lr;
            int ao = ra * 64 + (((ks2 * 4 + lg) ^ (ra & 7)) << 3);
            aw[ks2] = *(const bf16x8*)(Wt + ao);
        }
        const short* VB = &Vbuf[cur][0];
#pragma unroll
        for (int dt = 0; dt < 4; ++dt) {
#pragma unroll
            for (int ks2 = 0; ks2 < 2; ++ks2) {
                int rv = dt * 16 + lr;
                int vo = rv * 64 + (((ks2 * 4 + lg) ^ (rv & 7)) << 3);
                bf16x8 vv = *(const bf16x8*)(VB + vo);
                Oa[dt] = MFMA32(aw[ks2], vv, Oa[dt]);
            }
        }
    }

    // context out as hi/lo bf16 rowmajor [8192][512]
    {
        const int h = bh & 7;
#pragma unroll
        for (int dt = 0; dt < 4; ++dt)
#pragma unroll
            for (int rr = 0; rr < 4; ++rr) {
                int gi = i0 + wave * 16 + lg * 4 + rr;
                size_t off = ((size_t)(b * 2048 + gi)) * 512 + h * 64 + dt * 16 + lr;
                float a = Oa[dt][rr];
                unsigned short hb = f2bf(a);
                Aho[off] = (short)hb;
                Alo[off] = (short)f2bf(a - bf2f(hb));
            }
    }
#undef LOADKH
#undef WRITEKH
#undef LOADK
#undef WRITEK
#undef LOADV
#undef WRITEV
}

// ---------------------------------------------------------------------------
extern "C" void kernel_launch(void* const* d_in, const int* in_sizes, int n_in,
                              void* d_out, int out_size, void* d_ws, size_t ws_size,
                              hipStream_t stream) {
    const float* q   = (const float*)d_in[0];
    const float* k   = (const float*)d_in[1];
    const float* v   = (const float*)d_in[2];
    const int*   msk = (const int*)d_in[3];
    const float* w_q = (const float*)d_in[4];
    const float* w_k = (const float*)d_in[5];
    const float* w_v = (const float*)d_in[6];
    const float* w_o = (const float*)d_in[7];

    float* out = (float*)d_out;                 // [B,S,D]
    float* P   = out + (size_t)B_ * S_ * D_;    // [B,H,S,S]

    // ws layout (~96 MB)
    short* qh = (short*)d_ws;                   // [8192][512] bf16 hi (later context hi)
    short* ql = qh + (size_t)4194304;
    short* kh = ql + (size_t)4194304;
    short* kl = kh + (size_t)4194304;
    short* vh = kl + (size_t)4194304;
    short* vl = vh + (size_t)4194304;
    short* Qh = vl + (size_t)4194304;           // head-major
    short* Ql = Qh + (size_t)4194304;
    short* Kh = Ql + (size_t)4194304;
    short* Kl = Kh + (size_t)4194304;
    short* Vt = Kl + (size_t)4194304;           // [32][64][2048] bf16 (V^T)
    unsigned long long* pk = (unsigned long long*)(Vt + (size_t)4194304);
    short* wqh = (short*)(pk + (size_t)262144); // 512x512 each
    short* wql = wqh + (size_t)262144;
    short* wkh = wql + (size_t)262144;
    short* wkl = wkh + (size_t)262144;
    short* wvh = wkl + (size_t)262144;
    short* wvl = wvh + (size_t)262144;
    short* woh = wvl + (size_t)262144;
    short* wol = woh + (size_t)262144;

    dim3 blk(256);
    dim3 gproj(M_ / 128, D_ / 64);              // (64, 8)

    hipLaunchKernelGGL(cvt_qkv, dim3(2048, 3), blk, 0, stream,
                       q, k, v, qh, ql, kh, kl, vh, vl);
    hipLaunchKernelGGL(cvt_w, dim3(128, 4), blk, 0, stream,
                       w_q, w_k, w_v, w_o, wqh, wql, wkh, wkl, wvh, wvl, woh, wol);

    hipLaunchKernelGGL((gemm_bf<1>), gproj, blk, 0, stream, qh, ql, wqh, wql,
                       (float*)nullptr, Qh, Ql);
    hipLaunchKernelGGL((gemm_bf<1>), gproj, blk, 0, stream, kh, kl, wkh, wkl,
                       (float*)nullptr, Kh, Kl);
    hipLaunchKernelGGL((gemm_bf<2>), gproj, blk, 0, stream, vh, vl, wvh, wvl,
                       (float*)nullptr, Vt, (short*)nullptr);

    hipLaunchKernelGGL(mask_pack, dim3(M_), blk, 0, stream, msk, pk);

    // context written into qh/ql (dead after Q-gemm) as hi/lo bf16
    hipLaunchKernelGGL(fused_attn, dim3(32, 32), blk, 0, stream,
                       Qh, Ql, Kh, Kl, Vt, pk, P, qh, ql);

    hipLaunchKernelGGL((gemm_bf<0>), gproj, blk, 0, stream, qh, ql, woh, wol,
                       out, (short*)nullptr, (short*)nullptr);
}

// Round 24
// 387.540 us; speedup vs baseline: 2.3768x; 1.0027x over previous
//
#include <hip/hip_runtime.h>
#include <hip/hip_bf16.h>
#include <cstdint>

constexpr int B_ = 4;
constexpr int S_ = 2048;
constexpr int D_ = 512;
constexpr int H_ = 8;
constexpr int DK_ = 64;
constexpr int M_ = B_ * S_;

typedef __attribute__((ext_vector_type(8))) short bf16x8;
typedef __attribute__((ext_vector_type(4))) short bf16x4;
typedef __attribute__((ext_vector_type(4))) float f32x4;

__device__ __forceinline__ unsigned short f2bf(float x) {
    unsigned u = __float_as_uint(x);
    return (unsigned short)((u + 0x7fffu + ((u >> 16) & 1u)) >> 16);
}
__device__ __forceinline__ float bf2f(unsigned short h) {
    return __uint_as_float(((unsigned)h) << 16);
}

#define MFMA32(a, b, c) __builtin_amdgcn_mfma_f32_16x16x32_bf16(a, b, c, 0, 0, 0)

// ---------------------------------------------------------------------------
// cvt body (verified): fp32 -> hi/lo bf16 at linear idx
// ---------------------------------------------------------------------------
__device__ __forceinline__ void cvt_body(const float* __restrict__ X,
                                         short* __restrict__ Xh,
                                         short* __restrict__ Xl, size_t idx) {
    float4 v0 = *reinterpret_cast<const float4*>(X + idx);
    float4 v1 = *reinterpret_cast<const float4*>(X + idx + 4);
    float f[8] = {v0.x, v0.y, v0.z, v0.w, v1.x, v1.y, v1.z, v1.w};
    short hh[8], ll[8];
#pragma unroll
    for (int e = 0; e < 8; ++e) {
        unsigned short hb = f2bf(f[e]);
        hh[e] = (short)hb;
        ll[e] = (short)f2bf(f[e] - bf2f(hb));
    }
    *(bf16x4*)(Xh + idx)     = (bf16x4){hh[0], hh[1], hh[2], hh[3]};
    *(bf16x4*)(Xh + idx + 4) = (bf16x4){hh[4], hh[5], hh[6], hh[7]};
    *(bf16x4*)(Xl + idx)     = (bf16x4){ll[0], ll[1], ll[2], ll[3]};
    *(bf16x4*)(Xl + idx + 4) = (bf16x4){ll[4], ll[5], ll[6], ll[7]};
}

// cvt_qkv: grid (2048, 3) -> q,k,v
__global__ __launch_bounds__(256) void cvt_qkv(
    const float* __restrict__ q, const float* __restrict__ k,
    const float* __restrict__ v,
    short* __restrict__ qh, short* __restrict__ ql,
    short* __restrict__ kh, short* __restrict__ kl,
    short* __restrict__ vh, short* __restrict__ vl) {
    const float* X; short *Xh, *Xl;
    if (blockIdx.y == 0)      { X = q; Xh = qh; Xl = ql; }
    else if (blockIdx.y == 1) { X = k; Xh = kh; Xl = kl; }
    else                      { X = v; Xh = vh; Xl = vl; }
    cvt_body(X, Xh, Xl, ((size_t)blockIdx.x * 256 + threadIdx.x) * 8);
}

// cvt_w: grid (128, 4) -> w_q, w_k, w_v, w_o
__global__ __launch_bounds__(256) void cvt_w(
    const float* __restrict__ wq, const float* __restrict__ wk,
    const float* __restrict__ wv, const float* __restrict__ wo,
    short* __restrict__ qh, short* __restrict__ ql,
    short* __restrict__ kh, short* __restrict__ kl,
    short* __restrict__ vh, short* __restrict__ vl,
    short* __restrict__ oh, short* __restrict__ ol) {
    const float* X; short *Xh, *Xl;
    if (blockIdx.y == 0)      { X = wq; Xh = qh; Xl = ql; }
    else if (blockIdx.y == 1) { X = wk; Xh = kh; Xl = kl; }
    else if (blockIdx.y == 2) { X = wv; Xh = vh; Xl = vl; }
    else                      { X = wo; Xh = oh; Xl = ol; }
    cvt_body(X, Xh, Xl, ((size_t)blockIdx.x * 256 + threadIdx.x) * 8);
}

// ---------------------------------------------------------------------------
// stage_bf (verified)
// ---------------------------------------------------------------------------
__device__ __forceinline__ void stage_bf(const short* __restrict__ srcH,
                                         const short* __restrict__ srcL,
                                         short* Hh, short* Hl, int tid, int rows) {
#pragma unroll
    for (int p = 0; p < rows / 32; ++p) {
        int idx = tid + p * 256;
        int r = idx >> 3;
        int cc = idx & 7;
        int off = r * 64 + ((cc ^ (r & 7)) << 3);
        *(bf16x8*)(Hh + off) = *(const bf16x8*)(srcH + (size_t)r * 512 + cc * 8);
        *(bf16x8*)(Hl + off) = *(const bf16x8*)(srcL + (size_t)r * 512 + cc * 8);
    }
}

// ---------------------------------------------------------------------------
// gemm_bf: C[m][n] = sum_k A[m][k]*W[n][k], pre-converted hi/lo bf16 inputs.
// EPI 0: fp32 C.  EPI 1: head-major hi/lo (Q/K).  EPI 2: head-major V^T bf16.
// ---------------------------------------------------------------------------
template <int EPI>
__global__ __launch_bounds__(256) void gemm_bf(const short* __restrict__ Ah_g,
                                               const short* __restrict__ Al_g,
                                               const short* __restrict__ Wh_g,
                                               const short* __restrict__ Wl_g,
                                               float* __restrict__ C,
                                               short* __restrict__ Ch,
                                               short* __restrict__ Cl) {
    __shared__ __align__(16) short Ah[8192];
    __shared__ __align__(16) short Al[8192];
    __shared__ __align__(16) short Wh[4096];
    __shared__ __align__(16) short Wl[4096];

    const int tid = threadIdx.x;
    const int wave = tid >> 6;
    const int lane = tid & 63;
    const int lg = lane >> 4;
    const int lr = lane & 15;
    const int bm = blockIdx.x * 128;
    const int bn = blockIdx.y * 64;

    f32x4 acc[2][4];
#pragma unroll
    for (int s = 0; s < 2; ++s)
#pragma unroll
        for (int n = 0; n < 4; ++n) acc[s][n] = (f32x4){0.f, 0.f, 0.f, 0.f};

    for (int k0 = 0; k0 < 512; k0 += 64) {
        stage_bf(Ah_g + (size_t)bm * 512 + k0, Al_g + (size_t)bm * 512 + k0, Ah, Al, tid, 128);
        stage_bf(Wh_g + (size_t)bn * 512 + k0, Wl_g + (size_t)bn * 512 + k0, Wh, Wl, tid, 64);
        __syncthreads();

#pragma unroll
        for (int ks = 0; ks < 2; ++ks) {
            bf16x8 ah[2], al[2];
#pragma unroll
            for (int sub = 0; sub < 2; ++sub) {
                int r = wave * 32 + sub * 16 + lr;
                int off = r * 64 + (((ks * 4 + lg) ^ (r & 7)) << 3);
                ah[sub] = *(const bf16x8*)(Ah + off);
                al[sub] = *(const bf16x8*)(Al + off);
            }
#pragma unroll
            for (int nsub = 0; nsub < 4; ++nsub) {
                int r = nsub * 16 + lr;
                int off = r * 64 + (((ks * 4 + lg) ^ (r & 7)) << 3);
                bf16x8 wh = *(const bf16x8*)(Wh + off);
                bf16x8 wl = *(const bf16x8*)(Wl + off);
#pragma unroll
                for (int sub = 0; sub < 2; ++sub) {
                    acc[sub][nsub] = MFMA32(ah[sub], wh, acc[sub][nsub]);
                    acc[sub][nsub] = MFMA32(ah[sub], wl, acc[sub][nsub]);
                    acc[sub][nsub] = MFMA32(al[sub], wh, acc[sub][nsub]);
                }
            }
        }
        __syncthreads();
    }

    if (EPI == 2) {
#pragma unroll
        for (int sub = 0; sub < 2; ++sub)
#pragma unroll
            for (int nsub = 0; nsub < 4; ++nsub)
#pragma unroll
                for (int rr = 0; rr < 4; ++rr) {
                    int rloc = wave * 32 + sub * 16 + lg * 4 + rr;
                    int cloc = nsub * 16 + lr;
                    short bv = (short)f2bf(acc[sub][nsub][rr]);
                    if (rloc < 64) Ah[rloc * 66 + cloc] = bv;
                    else           Al[(rloc - 64) * 66 + cloc] = bv;
                }
        __syncthreads();
        const int dk = tid >> 2;
        const int j0l = (tid & 3) * 32;
        const short* src = (j0l < 64) ? Ah : Al;
        const int jb = j0l & 63;
        const int h = bn >> 6;
        const int bq = bm >> 11;
        short* dst = Ch + ((size_t)((bq * 8 + h) * 64 + dk)) * 2048 + (bm & 2047) + j0l;
#pragma unroll
        for (int qq = 0; qq < 4; ++qq) {
            bf16x8 o;
#pragma unroll
            for (int e = 0; e < 8; ++e)
                o[e] = src[(jb + qq * 8 + e) * 66 + dk];
            *(bf16x8*)(dst + qq * 8) = o;
        }
        return;
    }

#pragma unroll
    for (int sub = 0; sub < 2; ++sub)
#pragma unroll
        for (int nsub = 0; nsub < 4; ++nsub)
#pragma unroll
            for (int rr = 0; rr < 4; ++rr) {
                int row = bm + wave * 32 + sub * 16 + lg * 4 + rr;
                int col = bn + nsub * 16 + lr;
                float a = acc[sub][nsub][rr];
                if (EPI == 0) {
                    C[(size_t)row * 512 + col] = a;
                } else {
                    unsigned short hb = f2bf(a);
                    size_t off = (((size_t)(row >> 11) * 8 + (col >> 6)) * 2048 +
                                  (row & 2047)) * 64 + (col & 63);
                    Ch[off] = (short)hb;
                    Cl[off] = (short)f2bf(a - bf2f(hb));
                }
            }
}

// ---------------------------------------------------------------------------
// mask_pack (unchanged)
// ---------------------------------------------------------------------------
__global__ __launch_bounds__(256) void mask_pack(const int* __restrict__ mask,
                                                 unsigned long long* __restrict__ pk) {
    const int row = blockIdx.x;
    const int tid = threadIdx.x;
    const int* mrow = mask + (size_t)row * 2048;
#pragma unroll
    for (int p = 0; p < 8; ++p) {
        int j = p * 256 + tid;
        unsigned long long bal = __ballot(mrow[j] != 0);
        if ((tid & 63) == 0) pk[(size_t)row * 32 + p * 4 + (tid >> 6)] = bal;
    }
}

// ---------------------------------------------------------------------------
// Fused attention v12 = round-23 kernel (V staged in LDS, verified 388 us)
// with sweep 1 pair-unrolled: Kbuf's 16K shorts act as FOUR K-hi buffers;
// 2 tiles per barrier (32 -> 16 barriers). Same write-after-read safety as
// the verified 2-buffer scheme (disjoint buffer pairs, one phase apart).
// Sweep 2 byte-identical to round 23.
// ---------------------------------------------------------------------------
__global__ __launch_bounds__(256, 2) void fused_attn(
    const short* __restrict__ Qh_g, const short* __restrict__ Ql_g,
    const short* __restrict__ Kh_g, const short* __restrict__ Kl_g,
    const short* __restrict__ Vt_g, const unsigned long long* __restrict__ pk,
    float* __restrict__ P, short* __restrict__ Aho, short* __restrict__ Alo) {
    __shared__ __align__(16) short Kbuf[2][2][4096];
    __shared__ __align__(16) short Vbuf[2][4096];
    __shared__ __align__(16) short Wt[4096];

    const int tid = threadIdx.x;
    const int wave = tid >> 6;
    const int lane = tid & 63;
    const int lg = lane >> 4;
    const int lr = lane & 15;

    const int wgid = blockIdx.y * 32 + blockIdx.x;
    const int xcd = wgid & 7;
    const int slot = wgid >> 3;
    const int bh = xcd * 4 + (slot & 3);
    const int i0 = (slot >> 2) * 64;
    const int b = bh >> 3;

    bf16x8 qh[2], ql[2];
    {
        const size_t qbase = ((size_t)bh * 2048 + i0 + wave * 16 + lr) * 64;
#pragma unroll
        for (int ks = 0; ks < 2; ++ks) {
            qh[ks] = *(const bf16x8*)(Qh_g + qbase + (ks * 4 + lg) * 8);
            ql[ks] = *(const bf16x8*)(Ql_g + qbase + (ks * 4 + lg) * 8);
        }
    }

    const int o0 = tid * 16;
    const int o1 = 4096 + tid * 16;
    const int s0 = o0 ^ (((o0 >> 7) & 7) << 4);
    const int s1 = o1 ^ (((o1 >> 7) & 7) << 4);

    // V staging geometry (verified round 23)
    const int vr0 = tid >> 3, vc0 = tid & 7;
    const int vr1 = (tid + 256) >> 3, vc1 = (tid + 256) & 7;
    const int vs0 = vr0 * 64 + ((vc0 ^ (vr0 & 7)) << 3);
    const int vs1 = vr1 * 64 + ((vc1 ^ (vr1 & 7)) << 3);
    const short* Vbase = Vt_g + (size_t)bh * 64 * 2048;

    bf16x8 Rh0, Rh1, Rl0, Rl1, Rv0, Rv1;
    bf16x8 Ph0, Ph1, Ph2, Ph3;
    short* KH4 = &Kbuf[0][0][0];   // 4 x 4096-short K-hi buffers (sweep 1)

#define LOADKH2(t0)                                                         \
    {                                                                       \
        const short* bK0 = Kh_g + ((size_t)bh * 2048 + (t0) * 64) * 64;     \
        const short* bK1 = bK0 + 4096;                                      \
        Ph0 = *(const bf16x8*)(bK0 + (o0 >> 1));                            \
        Ph1 = *(const bf16x8*)(bK0 + (o1 >> 1));                            \
        Ph2 = *(const bf16x8*)(bK1 + (o0 >> 1));                            \
        Ph3 = *(const bf16x8*)(bK1 + (o1 >> 1));                            \
    }
#define WRITEKH2(base)                                                      \
    {                                                                       \
        *(bf16x8*)(KH4 + (base) * 4096 + (s0 >> 1)) = Ph0;                  \
        *(bf16x8*)(KH4 + (base) * 4096 + (s1 >> 1)) = Ph1;                  \
        *(bf16x8*)(KH4 + (base + 1) * 4096 + (s0 >> 1)) = Ph2;              \
        *(bf16x8*)(KH4 + (base + 1) * 4096 + (s1 >> 1)) = Ph3;              \
    }
#define LOADK(t)                                                            \
    {                                                                       \
        const short* bKh = Kh_g + ((size_t)bh * 2048 + (t) * 64) * 64;      \
        const short* bKl = Kl_g + ((size_t)bh * 2048 + (t) * 64) * 64;      \
        Rh0 = *(const bf16x8*)(bKh + (o0 >> 1));                            \
        Rh1 = *(const bf16x8*)(bKh + (o1 >> 1));                            \
        Rl0 = *(const bf16x8*)(bKl + (o0 >> 1));                            \
        Rl1 = *(const bf16x8*)(bKl + (o1 >> 1));                            \
    }
#define WRITEK(cur)                                                         \
    {                                                                       \
        *(bf16x8*)(&Kbuf[cur][0][0] + (s0 >> 1)) = Rh0;                     \
        *(bf16x8*)(&Kbuf[cur][0][0] + (s1 >> 1)) = Rh1;                     \
        *(bf16x8*)(&Kbuf[cur][1][0] + (s0 >> 1)) = Rl0;                     \
        *(bf16x8*)(&Kbuf[cur][1][0] + (s1 >> 1)) = Rl1;                     \
    }
#define LOADV(t)                                                            \
    {                                                                       \
        const short* bV = Vbase + (t) * 64;                                 \
        Rv0 = *(const bf16x8*)(bV + (size_t)vr0 * 2048 + vc0 * 8);          \
        Rv1 = *(const bf16x8*)(bV + (size_t)vr1 * 2048 + vc1 * 8);          \
    }
#define WRITEV(cur)                                                         \
    {                                                                       \
        *(bf16x8*)(&Vbuf[cur][0] + vs0) = Rv0;                              \
        *(bf16x8*)(&Vbuf[cur][0] + vs1) = Rv1;                              \
    }

    const size_t pkrow = (size_t)b * 2048 + i0 + wave * 16 + lg * 4;

    // ===== sweep 1 (lite, pair-unrolled): l = sum_j exp(s_hi), 16 barriers =====
    float l_[4] = {0.f, 0.f, 0.f, 0.f};

    LOADKH2(0);
    for (int p = 0; p < 16; ++p) {
        const int base = (p & 1) * 2;
        WRITEKH2(base);
        if (p < 15) LOADKH2(2 * (p + 1));
        unsigned long long pkv[2][4];
#pragma unroll
        for (int u = 0; u < 2; ++u)
#pragma unroll
            for (int rr = 0; rr < 4; ++rr)
                pkv[u][rr] = pk[(pkrow + rr) * 32 + 2 * p + u];
        __syncthreads();

#pragma unroll
        for (int u = 0; u < 2; ++u) {
            const short* KH = KH4 + (base + u) * 4096;
#pragma unroll
            for (int jt = 0; jt < 4; ++jt) {
                f32x4 s = (f32x4){0.f, 0.f, 0.f, 0.f};
                int r = jt * 16 + lr;
#pragma unroll
                for (int ks = 0; ks < 2; ++ks) {
                    int off = (r * 128 + (ks * 4 + lg) * 16) ^ ((r & 7) << 4);
                    bf16x8 kh = *(const bf16x8*)(KH + (off >> 1));
                    s = MFMA32(qh[ks], kh, s);
                }
#pragma unroll
                for (int rr = 0; rr < 4; ++rr) {
                    bool mk = (pkv[u][rr] >> (jt * 16 + lr)) & 1ull;
                    l_[rr] += mk ? 0.f : __expf(s[rr] * 0.125f);
                }
            }
        }
    }

    // cross-lane sum of l over the 16 lr lanes
#pragma unroll
    for (int rr = 0; rr < 4; ++rr) {
        float l = l_[rr];
#pragma unroll
        for (int d = 1; d < 16; d <<= 1) l += __shfl_xor(l, d);
        l_[rr] = l;
    }

    float invl[4];
#pragma unroll
    for (int rr = 0; rr < 4; ++rr) invl[rr] = 1.0f / fmaxf(l_[rr], 1e-37f);

    // make sure all waves are done reading sweep-1 buffers before sweep 2
    __syncthreads();

    // ====================== sweep 2: weights + P + PV ======================
    f32x4 Oa[4];
#pragma unroll
    for (int dt = 0; dt < 4; ++dt) Oa[dt] = (f32x4){0.f, 0.f, 0.f, 0.f};

    LOADK(0);
    LOADV(0);
    for (int t = 0; t < 32; ++t) {
        const int cur = t & 1;
        WRITEK(cur);
        WRITEV(cur);
        if (t < 31) { LOADK(t + 1); LOADV(t + 1); }
        unsigned long long pkv[4];
#pragma unroll
        for (int rr = 0; rr < 4; ++rr) pkv[rr] = pk[(pkrow + rr) * 32 + t];
        __syncthreads();

        const short* KH = &Kbuf[cur][0][0];
        const short* KL = &Kbuf[cur][1][0];
#pragma unroll
        for (int jt = 0; jt < 4; ++jt) {
            f32x4 s = (f32x4){0.f, 0.f, 0.f, 0.f};
            int r = jt * 16 + lr;
#pragma unroll
            for (int ks = 0; ks < 2; ++ks) {
                int off = (r * 128 + (ks * 4 + lg) * 16) ^ ((r & 7) << 4);
                bf16x8 kh = *(const bf16x8*)(KH + (off >> 1));
                bf16x8 kl = *(const bf16x8*)(KL + (off >> 1));
                s = MFMA32(qh[ks], kh, s);
                s = MFMA32(qh[ks], kl, s);
                s = MFMA32(ql[ks], kh, s);
            }
#pragma unroll
            for (int rr = 0; rr < 4; ++rr) {
                bool mk = (pkv[rr] >> (jt * 16 + lr)) & 1ull;
                float w = mk ? 0.f : __expf(s[rr] * 0.125f) * invl[rr];
                int rw = wave * 16 + lg * 4 + rr;
                int wo = rw * 64 + (((jt * 2 + (lr >> 3)) ^ (rw & 7)) << 3) + (lr & 7);
                Wt[wo] = (short)f2bf(w);
            }
        }

        // P write (wave-own rows): bf16 Wt -> fp32, coalesced 16B stores
        {
            int rp = wave * 16 + (lane >> 2);
            int c2 = (lane & 3) * 2;
            int po0 = rp * 64 + (((c2 + 0) ^ (rp & 7)) << 3);
            int po1 = rp * 64 + (((c2 + 1) ^ (rp & 7)) << 3);
            bf16x8 wa = *(const bf16x8*)(Wt + po0);
            bf16x8 wb = *(const bf16x8*)(Wt + po1);
            float* Prow = P + ((size_t)bh * 2048 + i0 + rp) * 2048 + t * 64 + (lane & 3) * 16;
#pragma unroll
            for (int q = 0; q < 2; ++q) {
                f32x4 oA = {bf2f((unsigned short)wa[q * 4 + 0]), bf2f((unsigned short)wa[q * 4 + 1]),
                            bf2f((unsigned short)wa[q * 4 + 2]), bf2f((unsigned short)wa[q * 4 + 3])};
                f32x4 oB = {bf2f((unsigned short)wb[q * 4 + 0]), bf2f((unsigned short)wb[q * 4 + 1]),
                            bf2f((unsigned short)wb[q * 4 + 2]), bf2f((unsigned short)wb[q * 4 + 3])};
                *(f32x4*)(Prow + q * 4) = oA;
                *(f32x4*)(Prow + 8 + q * 4) = oB;
            }
        }

        // PV: A-frag = wave's own Wt rows, B-frag = V tile from LDS (shared)
        bf16x8 aw[2];
#pragma unroll
        for (int ks2 = 0; ks2 < 2; ++ks2) {
            int ra = wave * 16 + lr;
            int ao = ra * 64 + (((ks2 * 4 + lg) ^ (ra & 7)) << 3);
            aw[ks2] = *(const bf16x8*)(Wt + ao);
        }
        const short* VB = &Vbuf[cur][0];
#pragma unroll
        for (int dt = 0; dt < 4; ++dt) {
#pragma unroll
            for (int ks2 = 0; ks2 < 2; ++ks2) {
                int rv = dt * 16 + lr;
                int vo = rv * 64 + (((ks2 * 4 + lg) ^ (rv & 7)) << 3);
                bf16x8 vv = *(const bf16x8*)(VB + vo);
                Oa[dt] = MFMA32(aw[ks2], vv, Oa[dt]);
            }
        }
    }

    // context out as hi/lo bf16 rowmajor [8192][512]
    {
        const int h = bh & 7;
#pragma unroll
        for (int dt = 0; dt < 4; ++dt)
#pragma unroll
            for (int rr = 0; rr < 4; ++rr) {
                int gi = i0 + wave * 16 + lg * 4 + rr;
                size_t off = ((size_t)(b * 2048 + gi)) * 512 + h * 64 + dt * 16 + lr;
                float a = Oa[dt][rr];
                unsigned short hb = f2bf(a);
                Aho[off] = (short)hb;
                Alo[off] = (short)f2bf(a - bf2f(hb));
            }
    }
#undef LOADKH2
#undef WRITEKH2
#undef LOADK
#undef WRITEK
#undef LOADV
#undef WRITEV
}

// ---------------------------------------------------------------------------
extern "C" void kernel_launch(void* const* d_in, const int* in_sizes, int n_in,
                              void* d_out, int out_size, void* d_ws, size_t ws_size,
                              hipStream_t stream) {
    const float* q   = (const float*)d_in[0];
    const float* k   = (const float*)d_in[1];
    const float* v   = (const float*)d_in[2];
    const int*   msk = (const int*)d_in[3];
    const float* w_q = (const float*)d_in[4];
    const float* w_k = (const float*)d_in[5];
    const float* w_v = (const float*)d_in[6];
    const float* w_o = (const float*)d_in[7];

    float* out = (float*)d_out;                 // [B,S,D]
    float* P   = out + (size_t)B_ * S_ * D_;    // [B,H,S,S]

    // ws layout (~96 MB)
    short* qh = (short*)d_ws;                   // [8192][512] bf16 hi (later context hi)
    short* ql = qh + (size_t)4194304;
    short* kh = ql + (size_t)4194304;
    short* kl = kh + (size_t)4194304;
    short* vh = kl + (size_t)4194304;
    short* vl = vh + (size_t)4194304;
    short* Qh = vl + (size_t)4194304;           // head-major
    short* Ql = Qh + (size_t)4194304;
    short* Kh = Ql + (size_t)4194304;
    short* Kl = Kh + (size_t)4194304;
    short* Vt = Kl + (size_t)4194304;           // [32][64][2048] bf16 (V^T)
    unsigned long long* pk = (unsigned long long*)(Vt + (size_t)4194304);
    short* wqh = (short*)(pk + (size_t)262144); // 512x512 each
    short* wql = wqh + (size_t)262144;
    short* wkh = wql + (size_t)262144;
    short* wkl = wkh + (size_t)262144;
    short* wvh = wkl + (size_t)262144;
    short* wvl = wvh + (size_t)262144;
    short* woh = wvl + (size_t)262144;
    short* wol = woh + (size_t)262144;

    dim3 blk(256);
    dim3 gproj(M_ / 128, D_ / 64);              // (64, 8)

    hipLaunchKernelGGL(cvt_qkv, dim3(2048, 3), blk, 0, stream,
                       q, k, v, qh, ql, kh, kl, vh, vl);
    hipLaunchKernelGGL(cvt_w, dim3(128, 4), blk, 0, stream,
                       w_q, w_k, w_v, w_o, wqh, wql, wkh, wkl, wvh, wvl, woh, wol);

    hipLaunchKernelGGL((gemm_bf<1>), gproj, blk, 0, stream, qh, ql, wqh, wql,
                       (float*)nullptr, Qh, Ql);
    hipLaunchKernelGGL((gemm_bf<1>), gproj, blk, 0, stream, kh, kl, wkh, wkl,
                       (float*)nullptr, Kh, Kl);
    hipLaunchKernelGGL((gemm_bf<2>), gproj, blk, 0, stream, vh, vl, wvh, wvl,
                       (float*)nullptr, Vt, (short*)nullptr);

    hipLaunchKernelGGL(mask_pack, dim3(M_), blk, 0, stream, msk, pk);

    // context written into qh/ql (dead after Q-gemm) as hi/lo bf16
    hipLaunchKernelGGL(fused_attn, dim3(32, 32), blk, 0, stream,
                       Qh, Ql, Kh, Kl, Vt, pk, P, qh, ql);

    hipLaunchKernelGGL((gemm_bf<0>), gproj, blk, 0, stream, qh, ql, woh, wol,
                       out, (short*)nullptr, (short*)nullptr);
}